// Round 19
// baseline (340.507 us; speedup 1.0000x reference)
//
#include <hip/hip_runtime.h>
#include <hip/hip_bf16.h>
#include <cstddef>

// ---------------------------------------------------------------------------
// Problem dims
// ---------------------------------------------------------------------------
#define VOCAB 50000
#define EDIM  200
#define HDIM  128
#define BB 16
#define RR 10
#define SS 20
#define WW 64
#define NSENT (BB*RR*SS)   // 3200 word-level sequences
#define NREV  (BB*RR)      // 160 sentence-level sequences
#define G3    (3*HDIM)     // 384 gate rows per direction
#define NPROJ (2*G3)       // 768

// ---------------------------------------------------------------------------
// bf16 + fast-math helpers
// ---------------------------------------------------------------------------
static __device__ __forceinline__ short f2bf(float f) {    // RNE
    union { float f; unsigned u; } v; v.f = f;
    unsigned r = v.u + 0x7FFFu + ((v.u >> 16) & 1u);
    return (short)(r >> 16);
}
static __device__ __forceinline__ short f2bf_t(float f) {  // truncate
    union { float f; unsigned u; } v; v.f = f;
    return (short)(v.u >> 16);
}
static __device__ __forceinline__ float bf2f(short s) {
    union { unsigned u; float f; } v;
    v.u = ((unsigned)(unsigned short)s) << 16;
    return v.f;
}
static __device__ __forceinline__ float frcp(float x) {
    return __builtin_amdgcn_rcpf(x);
}
static __device__ __forceinline__ float fsigmoid(float x) {
    return frcp(1.f + __expf(-x));
}
static __device__ __forceinline__ float ftanh(float x) {
    float y = __expf(-2.f * fabsf(x));
    float t = (1.f - y) * frcp(1.f + y);
    return copysignf(t, x);
}

using bf16x8 = __attribute__((ext_vector_type(8))) short;
using f32x4  = __attribute__((ext_vector_type(4))) float;

// ---------------------------------------------------------------------------
// preconv_all: ONE launch converting all 4 weight matrices to split-bf16
// blobs (wWih_f/b: 200->224 pad; sWih_f/b: 128).
// ---------------------------------------------------------------------------
#define NG1 (384 * 224 / 8)   // 10752
#define NG2 (384 * 128 / 8)   // 6144

__global__ __launch_bounds__(256) void preconv_all(
    const float* __restrict__ wWih_f, const float* __restrict__ wWih_b,
    const float* __restrict__ sWih_f, const float* __restrict__ sWih_b,
    short* __restrict__ Bw_hi, short* __restrict__ Bw_lo,
    short* __restrict__ Sw_hi, short* __restrict__ Sw_lo)
{
    int g = blockIdx.x * 256 + threadIdx.x;
    const float* src; short* hi; short* lo; int KREAL, KPAD;
    if (g < NG1) {
        src = wWih_f; hi = Bw_hi; lo = Bw_lo; KREAL = 200; KPAD = 224;
    } else if (g < 2 * NG1) {
        g -= NG1;
        src = wWih_b; hi = Bw_hi + 384 * 224; lo = Bw_lo + 384 * 224;
        KREAL = 200; KPAD = 224;
    } else if (g < 2 * NG1 + NG2) {
        g -= 2 * NG1;
        src = sWih_f; hi = Sw_hi; lo = Sw_lo; KREAL = 128; KPAD = 128;
    } else if (g < 2 * NG1 + 2 * NG2) {
        g -= 2 * NG1 + NG2;
        src = sWih_b; hi = Sw_hi + 384 * 128; lo = Sw_lo + 384 * 128;
        KREAL = 128; KPAD = 128;
    } else return;

    int row = g / (KPAD / 8);
    int k   = (g % (KPAD / 8)) * 8;
    float v[8];
    if (k < KREAL) {
        const float* p = src + (size_t)row * KREAL + k;
        float4 a = *(const float4*)p;
        float4 b = *(const float4*)(p + 4);
        v[0]=a.x; v[1]=a.y; v[2]=a.z; v[3]=a.w;
        v[4]=b.x; v[5]=b.y; v[6]=b.z; v[7]=b.w;
    } else {
        #pragma unroll
        for (int j = 0; j < 8; ++j) v[j] = 0.f;
    }
    bf16x8 h, l;
    #pragma unroll
    for (int j = 0; j < 8; ++j) {
        short t = f2bf_t(v[j]);
        h[j] = t;
        l[j] = f2bf(v[j] - bf2f(t));
    }
    *(bf16x8*)&hi[(size_t)row * KPAD + k] = h;
    *(bf16x8*)&lo[(size_t)row * KPAD + k] = l;
}

// ---------------------------------------------------------------------------
// gemm_v6: split-bf16 MFMA GEMM, XCD-friendly grid, coalesced LDS-staged
// epilogue writing the table as BF16 (RNE):
//   Cbf16[M x 768] = A[M x KREAL] @ Bblob[768 x KPAD]^T + [bias0;bias1]
// ---------------------------------------------------------------------------
template<int KREAL, int KPAD, bool AVG>
__global__ __launch_bounds__(256, 2) void gemm_v6(
    const float* __restrict__ A0, const float* __restrict__ A1, int M,
    const short* __restrict__ Bhi_g, const short* __restrict__ Blo_g,
    const float* __restrict__ bias0, const float* __restrict__ bias1,
    short* __restrict__ C)
{
    const int rt = blockIdx.x;
    const int ct = blockIdx.y;
    const int tid = threadIdx.x;
    const int lane = tid & 63;
    const int wid  = tid >> 6;
    const int rlane = lane & 15;
    const int kgrp  = lane >> 4;

    const int rowBase = rt * 128;
    const int colBase = ct * 128;

    __shared__ __align__(16) short smem[4 * 128 * 40];   // 40960 B
    short (*Ahi)[40] = (short(*)[40])(smem);
    short (*Alo)[40] = (short(*)[40])(smem + 5120);
    short (*Bhi)[40] = (short(*)[40])(smem + 10240);
    short (*Blo)[40] = (short(*)[40])(smem + 15360);

    const int wrow = (wid >> 1) * 64;
    const int wcol = (wid & 1) * 64;

    f32x4 acc[4][4];
    #pragma unroll
    for (int i = 0; i < 4; ++i)
        #pragma unroll
        for (int j = 0; j < 4; ++j) acc[i][j] = {0.f, 0.f, 0.f, 0.f};

    const int srow = tid >> 1;
    const int skh  = (tid & 1) << 4;
    const int grow = rowBase + srow;
    const size_t brow = (size_t)(colBase + srow) * KPAD;

    for (int k0 = 0; k0 < KPAD; k0 += 32) {
        {
            float v[16];
            #pragma unroll
            for (int i = 0; i < 4; ++i) {
                const int k = k0 + skh + i * 4;
                float4 x = {0.f, 0.f, 0.f, 0.f};
                if (grow < M && k + 3 < KREAL) {
                    x = *(const float4*)&A0[(size_t)grow * KREAL + k];
                    if (AVG) {
                        float4 y = *(const float4*)&A1[(size_t)grow * KREAL + k];
                        x.x = 0.5f * (x.x + y.x); x.y = 0.5f * (x.y + y.y);
                        x.z = 0.5f * (x.z + y.z); x.w = 0.5f * (x.w + y.w);
                    }
                }
                v[4*i+0] = x.x; v[4*i+1] = x.y; v[4*i+2] = x.z; v[4*i+3] = x.w;
            }
            bf16x8 h0, h1, l0, l1;
            #pragma unroll
            for (int i = 0; i < 8; ++i) {
                short a = f2bf_t(v[i]);
                h0[i] = a; l0[i] = f2bf(v[i] - bf2f(a));
                short b = f2bf_t(v[i + 8]);
                h1[i] = b; l1[i] = f2bf(v[i + 8] - bf2f(b));
            }
            *(bf16x8*)&Ahi[srow][skh]     = h0;
            *(bf16x8*)&Ahi[srow][skh + 8] = h1;
            *(bf16x8*)&Alo[srow][skh]     = l0;
            *(bf16x8*)&Alo[srow][skh + 8] = l1;
        }
        *(bf16x8*)&Bhi[srow][skh]     = *(const bf16x8*)&Bhi_g[brow + k0 + skh];
        *(bf16x8*)&Bhi[srow][skh + 8] = *(const bf16x8*)&Bhi_g[brow + k0 + skh + 8];
        *(bf16x8*)&Blo[srow][skh]     = *(const bf16x8*)&Blo_g[brow + k0 + skh];
        *(bf16x8*)&Blo[srow][skh + 8] = *(const bf16x8*)&Blo_g[brow + k0 + skh + 8];
        __syncthreads();
        bf16x8 ah[4], al[4], bh[4], bl[4];
        #pragma unroll
        for (int mr = 0; mr < 4; ++mr) {
            ah[mr] = *(const bf16x8*)&Ahi[wrow + mr * 16 + rlane][kgrp * 8];
            al[mr] = *(const bf16x8*)&Alo[wrow + mr * 16 + rlane][kgrp * 8];
        }
        #pragma unroll
        for (int nc = 0; nc < 4; ++nc) {
            bh[nc] = *(const bf16x8*)&Bhi[wcol + nc * 16 + rlane][kgrp * 8];
            bl[nc] = *(const bf16x8*)&Blo[wcol + nc * 16 + rlane][kgrp * 8];
        }
        #pragma unroll
        for (int mr = 0; mr < 4; ++mr)
            #pragma unroll
            for (int nc = 0; nc < 4; ++nc) {
                acc[mr][nc] = __builtin_amdgcn_mfma_f32_16x16x32_bf16(
                    ah[mr], bh[nc], acc[mr][nc], 0, 0, 0);
                acc[mr][nc] = __builtin_amdgcn_mfma_f32_16x16x32_bf16(
                    ah[mr], bl[nc], acc[mr][nc], 0, 0, 0);
                acc[mr][nc] = __builtin_amdgcn_mfma_f32_16x16x32_bf16(
                    al[mr], bh[nc], acc[mr][nc], 0, 0, 0);
            }
        __syncthreads();
    }

    // ---- epilogue: acc -> LDS f32 [128][68] -> bf16 short8 stores ----
    const float* bs = (colBase < G3) ? bias0 : bias1;
    const int bcol = (colBase < G3) ? colBase : (colBase - G3);
    float* ldsf = (float*)smem;           // 128*68*4 = 34816 B <= 40960
    #pragma unroll
    for (int half = 0; half < 2; ++half) {
        __syncthreads();
        if ((wid & 1) == half) {
            #pragma unroll
            for (int nc = 0; nc < 4; ++nc) {
                const int c = nc * 16 + rlane;
                const float bv = bs[bcol + half * 64 + c];
                #pragma unroll
                for (int mr = 0; mr < 4; ++mr)
                    #pragma unroll
                    for (int r = 0; r < 4; ++r)
                        ldsf[(wrow + mr * 16 + kgrp * 4 + r) * 68 + c] =
                            acc[mr][nc][r] + bv;
            }
        }
        __syncthreads();
        const int row = tid >> 1;
        const int ch  = (tid & 1) * 32;
        if (rowBase + row < M) {
            short* cp = C + (size_t)(rowBase + row) * NPROJ
                          + colBase + half * 64 + ch;
            #pragma unroll
            for (int i = 0; i < 4; ++i) {
                bf16x8 o;
                #pragma unroll
                for (int j = 0; j < 8; ++j)
                    o[j] = f2bf(ldsf[row * 68 + ch + i * 8 + j]);
                *(bf16x8*)(cp + i * 8) = o;
            }
        }
    }
}

// ---------------------------------------------------------------------------
// Single-block counting sort for BOTH length arrays.
// ---------------------------------------------------------------------------
__global__ __launch_bounds__(256) void sort_all(
    const int* __restrict__ len1, int* __restrict__ order1,
    const int* __restrict__ len2, int* __restrict__ order2)
{
    __shared__ int hist[65];
    const int tid = threadIdx.x;

    for (int i = tid; i < 65; i += 256) hist[i] = 0;
    __syncthreads();
    for (int i = tid; i < NSENT; i += 256) atomicAdd(&hist[len1[i]], 1);
    __syncthreads();
    if (tid == 0) {
        int acc = 0;
        for (int l = 1; l <= WW; ++l) { int c = hist[l]; hist[l] = acc; acc += c; }
    }
    __syncthreads();
    for (int i = tid; i < NSENT; i += 256) {
        int pos = atomicAdd(&hist[len1[i]], 1);
        order1[pos] = i;
    }
    __syncthreads();
    for (int i = tid; i < 65; i += 256) hist[i] = 0;
    __syncthreads();
    for (int i = tid; i < NREV; i += 256) atomicAdd(&hist[len2[i]], 1);
    __syncthreads();
    if (tid == 0) {
        int acc = 0;
        for (int l = 1; l <= SS; ++l) { int c = hist[l]; hist[l] = acc; acc += c; }
    }
    __syncthreads();
    for (int i = tid; i < NREV; i += 256) {
        int pos = atomicAdd(&hist[len2[i]], 1);
        order2[pos] = i;
    }
}

// ---------------------------------------------------------------------------
// MFMA GRU scan, single-bf16 h recurrence, BF16 table gathers.
// Structure = round-18 proven (fused gate, depth-2 xg prefetch via 2-body
// unroll, rcp gates, 24 MFMA/step, LDS ~13 KB, VGPR ~96 -> 2 blocks/CU).
// ---------------------------------------------------------------------------
template<bool WORD, int TMAX>
__global__ __launch_bounds__(512, 2) void gru_mfma(
    const short* __restrict__ table,    // [*, 768] BF16 projected table
    const int*   __restrict__ tokens,
    const int*   __restrict__ lengths,
    const int*   __restrict__ order,
    const float* __restrict__ Whh_f, const float* __restrict__ Whh_b,
    const float* __restrict__ bhh_f, const float* __restrict__ bhh_b,
    float* __restrict__ hout_f, float* __restrict__ hout_b,
    int numSeq, int numTiles)
{
    const int dir  = (blockIdx.x >= numTiles) ? 1 : 0;
    const int rawt = dir ? (blockIdx.x - numTiles) : blockIdx.x;
    const int tile = numTiles - 1 - rawt;      // longest tiles first
    const int base = tile * 16;
    const int tid  = threadIdx.x;              // 0..511
    const int lane = tid & 63;
    const int wid  = tid >> 6;                 // 0..7
    const int rlane = lane & 15;
    const int kgrp  = lane >> 4;               // 0..3
    const int e = wid * 16 + rlane;            // this lane's gate element

    __shared__ __align__(16) short sh_hi[2][16][136];
    __shared__ int sh_len[16];
    __shared__ int sh_ord[16];
    __shared__ int sh_tok[WORD ? 16 * WW : 1];
    __shared__ int sh_maxlen;

    const float* Whh = dir ? Whh_b : Whh_f;
    const float* bhh = dir ? bhh_b : bhh_f;
    bf16x8 Bhi[3][4], Blo[3][4];
    float bb[3];
    #pragma unroll
    for (int nt = 0; nt < 3; ++nt) {
        const int cb = nt * HDIM + wid * 16;
        const float* wrow = Whh + (size_t)(cb + rlane) * HDIM;
        bb[nt] = bhh[cb + rlane];
        #pragma unroll
        for (int kc = 0; kc < 4; ++kc) {
            const float* wp = wrow + kc * 32 + kgrp * 8;
            float4 w0 = *(const float4*)wp;
            float4 w1 = *(const float4*)(wp + 4);
            float wv[8] = {w0.x, w0.y, w0.z, w0.w, w1.x, w1.y, w1.z, w1.w};
            #pragma unroll
            for (int j = 0; j < 8; ++j) {
                short hi = f2bf_t(wv[j]);
                Bhi[nt][kc][j] = hi;
                Blo[nt][kc][j] = f2bf(wv[j] - bf2f(hi));
            }
        }
    }

    if (tid < 16) {
        int pos = base + tid;
        int seq = (pos < numSeq) ? order[pos] : -1;
        sh_ord[tid] = seq;
        sh_len[tid] = (seq >= 0) ? lengths[seq] : 0;
    }
    __syncthreads();
    if (WORD) {
        for (int f = tid; f < 16 * WW; f += 512) {
            int s = f >> 6;
            int seq = sh_ord[s];
            sh_tok[f] = (seq >= 0) ? tokens[(size_t)seq * WW + (f & 63)] : 0;
        }
    }
    for (int u = tid; u < 2 * 16 * 136; u += 512)
        ((short*)sh_hi)[u] = 0;
    if (tid == 0) {
        int m = 0;
        for (int s = 0; s < 16; ++s) m = max(m, sh_len[s]);
        sh_maxlen = m;
    }
    int lens[4], ords[4];
    #pragma unroll
    for (int j = 0; j < 4; ++j) {
        lens[j] = sh_len[4 * kgrp + j];
        ords[j] = sh_ord[4 * kgrp + j];
    }
    __syncthreads();
    const int maxlen = sh_maxlen;

    auto fetch_xg = [&](int t, float* fr, float* fz, float* fn) {
        #pragma unroll
        for (int j = 0; j < 4; ++j) {
            fr[j] = 0.f; fz[j] = 0.f; fn[j] = 0.f;
            if (t < lens[j]) {
                int tt = dir ? (lens[j] - 1 - t) : t;
                size_t row;
                if (WORD) row = (size_t)sh_tok[(4 * kgrp + j) * WW + tt];
                else      row = (size_t)ords[j] * TMAX + tt;
                const short* xg = table + row * NPROJ + dir * G3 + e;
                fr[j] = bf2f(xg[0]);
                fz[j] = bf2f(xg[HDIM]);
                fn[j] = bf2f(xg[2 * HDIM]);
            }
        }
    };

    float hold[4] = {0.f, 0.f, 0.f, 0.f};
    float pAr[4], pAz[4], pAn[4];   // xg for even steps
    float pBr[4], pBz[4], pBn[4];   // xg for odd steps
    fetch_xg(0, pAr, pAz, pAn);
    fetch_xg(1, pBr, pBz, pBn);

#define GRU_STEP(T, PR, PZ, PN)                                               \
    {                                                                         \
        const int cur = (T) & 1, nxt = cur ^ 1;                               \
        bf16x8 ah[4];                                                         \
        _Pragma("unroll")                                                     \
        for (int kc = 0; kc < 4; ++kc)                                        \
            ah[kc] = *(const bf16x8*)&sh_hi[cur][rlane][kc * 32 + kgrp * 8];  \
        f32x4 acc[3];                                                         \
        _Pragma("unroll")                                                     \
        for (int nt = 0; nt < 3; ++nt) {                                      \
            acc[nt] = {0.f, 0.f, 0.f, 0.f};                                   \
            _Pragma("unroll")                                                 \
            for (int kc = 0; kc < 4; ++kc)                                    \
                acc[nt] = __builtin_amdgcn_mfma_f32_16x16x32_bf16(            \
                    ah[kc], Bhi[nt][kc], acc[nt], 0, 0, 0);                   \
            _Pragma("unroll")                                                 \
            for (int kc = 0; kc < 4; ++kc)                                    \
                acc[nt] = __builtin_amdgcn_mfma_f32_16x16x32_bf16(            \
                    ah[kc], Blo[nt][kc], acc[nt], 0, 0, 0);                   \
        }                                                                     \
        _Pragma("unroll")                                                     \
        for (int j = 0; j < 4; ++j) {                                         \
            if ((T) < lens[j]) {                                              \
                float hgr = acc[0][j] + bb[0];                                \
                float hgz = acc[1][j] + bb[1];                                \
                float hgn = acc[2][j] + bb[2];                                \
                float rg = fsigmoid(PR[j] + hgr);                             \
                float zg = fsigmoid(PZ[j] + hgz);                             \
                float ng = ftanh(PN[j] + rg * hgn);                           \
                hold[j] = (1.f - zg) * ng + zg * hold[j];                     \
            }                                                                 \
        }                                                                     \
        fetch_xg((T) + 2, PR, PZ, PN);                                        \
        _Pragma("unroll")                                                     \
        for (int j = 0; j < 4; ++j) {                                         \
            const int s = 4 * kgrp + j;                                       \
            sh_hi[nxt][s][e] = f2bf(hold[j]);                                 \
        }                                                                     \
        __syncthreads();                                                      \
    }

    int t = 0;
    for (; t + 1 < maxlen; t += 2) {
        GRU_STEP(t,     pAr, pAz, pAn);
        GRU_STEP(t + 1, pBr, pBz, pBn);
    }
    if (t < maxlen) {
        GRU_STEP(t, pAr, pAz, pAn);
    }
#undef GRU_STEP

    float* hout = dir ? hout_b : hout_f;
    #pragma unroll
    for (int j = 0; j < 4; ++j) {
        if (ords[j] >= 0)
            hout[(size_t)ords[j] * HDIM + e] = hold[j];
    }
}

// ---------------------------------------------------------------------------
// Head + mean
// ---------------------------------------------------------------------------
__global__ __launch_bounds__(64) void head_kernel(
    const float* __restrict__ hsf, const float* __restrict__ hsb,
    const float* __restrict__ fc1_w, const float* __restrict__ fc1_b,
    const float* __restrict__ fc2_w, const float* __restrict__ fc2_b,
    float* __restrict__ out)
{
    const int br = blockIdx.x;
    const int j = threadIdx.x;
    __shared__ float rev[HDIM];
    for (int ee = j; ee < HDIM; ee += 64)
        rev[ee] = 0.5f * (hsf[(size_t)br * HDIM + ee] + hsb[(size_t)br * HDIM + ee]);
    __syncthreads();
    float acc = 0.f;
    #pragma unroll
    for (int k = 0; k < HDIM; ++k)
        acc = fmaf(fc1_w[(size_t)j * HDIM + k], rev[k], acc);
    acc += fc1_b[j];
    const float alpha = 1.6732632423543772f;
    const float scale = 1.0507009873554805f;
    float h1 = scale * (acc > 0.f ? acc : alpha * (expf(acc) - 1.f));
    float contrib = h1 * fc2_w[j];
    #pragma unroll
    for (int off = 32; off > 0; off >>= 1)
        contrib += __shfl_down(contrib, off);
    if (j == 0) out[16 + br] = contrib + fc2_b[0];
}

__global__ void mean_kernel(float* __restrict__ out)
{
    int b = threadIdx.x;
    if (b < BB) {
        float s = 0.f;
        for (int r = 0; r < RR; ++r) s += out[16 + b * RR + r];
        out[b] = s / (float)RR;
    }
}

// ---------------------------------------------------------------------------
// Launch
// ---------------------------------------------------------------------------
extern "C" void kernel_launch(void* const* d_in, const int* in_sizes, int n_in,
                              void* d_out, int out_size, void* d_ws, size_t ws_size,
                              hipStream_t stream)
{
    const int*   inputs       = (const int*)d_in[0];
    const int*   sent_lengths = (const int*)d_in[1];
    const int*   sent_counts  = (const int*)d_in[2];
    const float* embed   = (const float*)d_in[3];
    const float* wWih_f  = (const float*)d_in[4];
    const float* wWhh_f  = (const float*)d_in[5];
    const float* wbih_f  = (const float*)d_in[6];
    const float* wbhh_f  = (const float*)d_in[7];
    const float* wWih_b  = (const float*)d_in[8];
    const float* wWhh_b  = (const float*)d_in[9];
    const float* wbih_b  = (const float*)d_in[10];
    const float* wbhh_b  = (const float*)d_in[11];
    const float* sWih_f  = (const float*)d_in[12];
    const float* sWhh_f  = (const float*)d_in[13];
    const float* sbih_f  = (const float*)d_in[14];
    const float* sbhh_f  = (const float*)d_in[15];
    const float* sWih_b  = (const float*)d_in[16];
    const float* sWhh_b  = (const float*)d_in[17];
    const float* sbih_b  = (const float*)d_in[18];
    const float* sbhh_b  = (const float*)d_in[19];
    const float* fc1_w   = (const float*)d_in[20];
    const float* fc1_b   = (const float*)d_in[21];
    const float* fc2_w   = (const float*)d_in[22];
    const float* fc2_b   = (const float*)d_in[23];

    float* ws = (float*)d_ws;
    const size_t projT_elems = (size_t)VOCAB * NPROJ;      // shorts
    const size_t xgs_elems   = (size_t)NSENT * NPROJ;      // shorts
    const size_t h_elems     = (size_t)NSENT * HDIM;       // f32
    const size_t hs_elems    = (size_t)NREV * HDIM;        // f32
    float* hf    = ws;
    float* hb    = hf + h_elems;
    float* hsf   = hb + h_elems;
    float* hsb   = hsf + hs_elems;
    int* order1  = (int*)(hsb + hs_elems);         // [NSENT]
    int* order2  = order1 + NSENT;                 // [NREV]
    short* projT = (short*)(order2 + NREV);        // [VOCAB*768] bf16
    short* xgs   = projT + projT_elems;            // [NSENT*768] bf16
    short* Bw_hi = xgs + xgs_elems;                // [768*224]
    short* Bw_lo = Bw_hi + 768 * 224;
    short* Sw_hi = Bw_lo + 768 * 224;              // [768*128]
    short* Sw_lo = Sw_hi + 768 * 128;

    size_t need = (2*h_elems + 2*hs_elems) * sizeof(float)
                + (NSENT + NREV) * sizeof(int)
                + (projT_elems + xgs_elems
                   + (size_t)(2 * 768 * 224 + 2 * 768 * 128)) * sizeof(short);
    if (ws_size < need) return;

    // 0) counting sort + merged weight-blob preconversion
    sort_all<<<1, 256, 0, stream>>>(sent_lengths, order1, sent_counts, order2);
    {
        int ng = 2 * NG1 + 2 * NG2;
        preconv_all<<<(ng + 255) / 256, 256, 0, stream>>>(
            wWih_f, wWih_b, sWih_f, sWih_b, Bw_hi, Bw_lo, Sw_hi, Sw_lo);
    }

    // 1) projected-embedding table -> BF16 (grid x=rt for L2-friendly A reads)
    {
        dim3 grid((VOCAB + 127) / 128, NPROJ / 128);    // 391 x 6
        gemm_v6<EDIM, 224, false><<<grid, 256, 0, stream>>>(
            embed, nullptr, VOCAB, Bw_hi, Bw_lo, wbih_f, wbih_b, projT);
    }
    // 2) word-level BiGRU last-h (bf16-table scan)
    {
        int numTiles = NSENT / 16;                      // 200
        gru_mfma<true, WW><<<2 * numTiles, 512, 0, stream>>>(
            projT, inputs, sent_lengths, order1,
            wWhh_f, wWhh_b, wbhh_f, wbhh_b,
            hf, hb, NSENT, numTiles);
    }
    // 3) sentence-level input projections -> BF16
    {
        dim3 grid((NSENT + 127) / 128, NPROJ / 128);    // 25 x 6
        gemm_v6<HDIM, HDIM, true><<<grid, 256, 0, stream>>>(
            hf, hb, NSENT, Sw_hi, Sw_lo, sbih_f, sbih_b, xgs);
    }
    // 4) sentence-level BiGRU last-h
    {
        int numTiles = NREV / 16;                       // 10
        gru_mfma<false, SS><<<2 * numTiles, 512, 0, stream>>>(
            xgs, nullptr, sent_counts, order2,
            sWhh_f, sWhh_b, sbhh_f, sbhh_b,
            hsf, hsb, NREV, numTiles);
    }
    // 5) FC head -> r_stars, then p_stars
    head_kernel<<<NREV, 64, 0, stream>>>(hsf, hsb, fc1_w, fc1_b, fc2_w, fc2_b,
                                         (float*)d_out);
    mean_kernel<<<1, 64, 0, stream>>>((float*)d_out);
}

// Round 20
// 293.049 us; speedup vs baseline: 1.1619x; 1.1619x over previous
//
#include <hip/hip_runtime.h>
#include <hip/hip_bf16.h>
#include <cstddef>

// ---------------------------------------------------------------------------
// Problem dims
// ---------------------------------------------------------------------------
#define VOCAB 50000
#define EDIM  200
#define HDIM  128
#define BB 16
#define RR 10
#define SS 20
#define WW 64
#define NSENT (BB*RR*SS)   // 3200 word-level sequences
#define NREV  (BB*RR)      // 160 sentence-level sequences
#define G3    (3*HDIM)     // 384 gate rows per direction
#define NPROJ (2*G3)       // 768

// ---------------------------------------------------------------------------
// bf16 + fast-math helpers
// ---------------------------------------------------------------------------
static __device__ __forceinline__ short f2bf(float f) {    // RNE
    union { float f; unsigned u; } v; v.f = f;
    unsigned r = v.u + 0x7FFFu + ((v.u >> 16) & 1u);
    return (short)(r >> 16);
}
static __device__ __forceinline__ short f2bf_t(float f) {  // truncate
    union { float f; unsigned u; } v; v.f = f;
    return (short)(v.u >> 16);
}
static __device__ __forceinline__ float bf2f(short s) {
    union { unsigned u; float f; } v;
    v.u = ((unsigned)(unsigned short)s) << 16;
    return v.f;
}
static __device__ __forceinline__ float frcp(float x) {
    return __builtin_amdgcn_rcpf(x);
}
static __device__ __forceinline__ float fsigmoid(float x) {
    return frcp(1.f + __expf(-x));
}
static __device__ __forceinline__ float ftanh(float x) {
    float y = __expf(-2.f * fabsf(x));
    float t = (1.f - y) * frcp(1.f + y);
    return copysignf(t, x);
}

using bf16x8 = __attribute__((ext_vector_type(8))) short;
using f32x4  = __attribute__((ext_vector_type(4))) float;

// ---------------------------------------------------------------------------
// preconv_all: ONE launch converting all 4 weight matrices to split-bf16
// blobs (wWih_f/b: 200->224 pad; sWih_f/b: 128).
// ---------------------------------------------------------------------------
#define NG1 (384 * 224 / 8)   // 10752
#define NG2 (384 * 128 / 8)   // 6144

__global__ __launch_bounds__(256) void preconv_all(
    const float* __restrict__ wWih_f, const float* __restrict__ wWih_b,
    const float* __restrict__ sWih_f, const float* __restrict__ sWih_b,
    short* __restrict__ Bw_hi, short* __restrict__ Bw_lo,
    short* __restrict__ Sw_hi, short* __restrict__ Sw_lo)
{
    int g = blockIdx.x * 256 + threadIdx.x;
    const float* src; short* hi; short* lo; int KREAL, KPAD;
    if (g < NG1) {
        src = wWih_f; hi = Bw_hi; lo = Bw_lo; KREAL = 200; KPAD = 224;
    } else if (g < 2 * NG1) {
        g -= NG1;
        src = wWih_b; hi = Bw_hi + 384 * 224; lo = Bw_lo + 384 * 224;
        KREAL = 200; KPAD = 224;
    } else if (g < 2 * NG1 + NG2) {
        g -= 2 * NG1;
        src = sWih_f; hi = Sw_hi; lo = Sw_lo; KREAL = 128; KPAD = 128;
    } else if (g < 2 * NG1 + 2 * NG2) {
        g -= 2 * NG1 + NG2;
        src = sWih_b; hi = Sw_hi + 384 * 128; lo = Sw_lo + 384 * 128;
        KREAL = 128; KPAD = 128;
    } else return;

    int row = g / (KPAD / 8);
    int k   = (g % (KPAD / 8)) * 8;
    float v[8];
    if (k < KREAL) {
        const float* p = src + (size_t)row * KREAL + k;
        float4 a = *(const float4*)p;
        float4 b = *(const float4*)(p + 4);
        v[0]=a.x; v[1]=a.y; v[2]=a.z; v[3]=a.w;
        v[4]=b.x; v[5]=b.y; v[6]=b.z; v[7]=b.w;
    } else {
        #pragma unroll
        for (int j = 0; j < 8; ++j) v[j] = 0.f;
    }
    bf16x8 h, l;
    #pragma unroll
    for (int j = 0; j < 8; ++j) {
        short t = f2bf_t(v[j]);
        h[j] = t;
        l[j] = f2bf(v[j] - bf2f(t));
    }
    *(bf16x8*)&hi[(size_t)row * KPAD + k] = h;
    *(bf16x8*)&lo[(size_t)row * KPAD + k] = l;
}

// ---------------------------------------------------------------------------
// gemm_v6: split-bf16 MFMA GEMM, XCD-friendly grid, coalesced LDS-staged
// epilogue writing the table as BF16 (RNE):
//   Cbf16[M x 768] = A[M x KREAL] @ Bblob[768 x KPAD]^T + [bias0;bias1]
// ---------------------------------------------------------------------------
template<int KREAL, int KPAD, bool AVG>
__global__ __launch_bounds__(256, 2) void gemm_v6(
    const float* __restrict__ A0, const float* __restrict__ A1, int M,
    const short* __restrict__ Bhi_g, const short* __restrict__ Blo_g,
    const float* __restrict__ bias0, const float* __restrict__ bias1,
    short* __restrict__ C)
{
    const int rt = blockIdx.x;
    const int ct = blockIdx.y;
    const int tid = threadIdx.x;
    const int lane = tid & 63;
    const int wid  = tid >> 6;
    const int rlane = lane & 15;
    const int kgrp  = lane >> 4;

    const int rowBase = rt * 128;
    const int colBase = ct * 128;

    __shared__ __align__(16) short smem[4 * 128 * 40];   // 40960 B
    short (*Ahi)[40] = (short(*)[40])(smem);
    short (*Alo)[40] = (short(*)[40])(smem + 5120);
    short (*Bhi)[40] = (short(*)[40])(smem + 10240);
    short (*Blo)[40] = (short(*)[40])(smem + 15360);

    const int wrow = (wid >> 1) * 64;
    const int wcol = (wid & 1) * 64;

    f32x4 acc[4][4];
    #pragma unroll
    for (int i = 0; i < 4; ++i)
        #pragma unroll
        for (int j = 0; j < 4; ++j) acc[i][j] = {0.f, 0.f, 0.f, 0.f};

    const int srow = tid >> 1;
    const int skh  = (tid & 1) << 4;
    const int grow = rowBase + srow;
    const size_t brow = (size_t)(colBase + srow) * KPAD;

    for (int k0 = 0; k0 < KPAD; k0 += 32) {
        {
            float v[16];
            #pragma unroll
            for (int i = 0; i < 4; ++i) {
                const int k = k0 + skh + i * 4;
                float4 x = {0.f, 0.f, 0.f, 0.f};
                if (grow < M && k + 3 < KREAL) {
                    x = *(const float4*)&A0[(size_t)grow * KREAL + k];
                    if (AVG) {
                        float4 y = *(const float4*)&A1[(size_t)grow * KREAL + k];
                        x.x = 0.5f * (x.x + y.x); x.y = 0.5f * (x.y + y.y);
                        x.z = 0.5f * (x.z + y.z); x.w = 0.5f * (x.w + y.w);
                    }
                }
                v[4*i+0] = x.x; v[4*i+1] = x.y; v[4*i+2] = x.z; v[4*i+3] = x.w;
            }
            bf16x8 h0, h1, l0, l1;
            #pragma unroll
            for (int i = 0; i < 8; ++i) {
                short a = f2bf_t(v[i]);
                h0[i] = a; l0[i] = f2bf(v[i] - bf2f(a));
                short b = f2bf_t(v[i + 8]);
                h1[i] = b; l1[i] = f2bf(v[i + 8] - bf2f(b));
            }
            *(bf16x8*)&Ahi[srow][skh]     = h0;
            *(bf16x8*)&Ahi[srow][skh + 8] = h1;
            *(bf16x8*)&Alo[srow][skh]     = l0;
            *(bf16x8*)&Alo[srow][skh + 8] = l1;
        }
        *(bf16x8*)&Bhi[srow][skh]     = *(const bf16x8*)&Bhi_g[brow + k0 + skh];
        *(bf16x8*)&Bhi[srow][skh + 8] = *(const bf16x8*)&Bhi_g[brow + k0 + skh + 8];
        *(bf16x8*)&Blo[srow][skh]     = *(const bf16x8*)&Blo_g[brow + k0 + skh];
        *(bf16x8*)&Blo[srow][skh + 8] = *(const bf16x8*)&Blo_g[brow + k0 + skh + 8];
        __syncthreads();
        bf16x8 ah[4], al[4], bh[4], bl[4];
        #pragma unroll
        for (int mr = 0; mr < 4; ++mr) {
            ah[mr] = *(const bf16x8*)&Ahi[wrow + mr * 16 + rlane][kgrp * 8];
            al[mr] = *(const bf16x8*)&Alo[wrow + mr * 16 + rlane][kgrp * 8];
        }
        #pragma unroll
        for (int nc = 0; nc < 4; ++nc) {
            bh[nc] = *(const bf16x8*)&Bhi[wcol + nc * 16 + rlane][kgrp * 8];
            bl[nc] = *(const bf16x8*)&Blo[wcol + nc * 16 + rlane][kgrp * 8];
        }
        #pragma unroll
        for (int mr = 0; mr < 4; ++mr)
            #pragma unroll
            for (int nc = 0; nc < 4; ++nc) {
                acc[mr][nc] = __builtin_amdgcn_mfma_f32_16x16x32_bf16(
                    ah[mr], bh[nc], acc[mr][nc], 0, 0, 0);
                acc[mr][nc] = __builtin_amdgcn_mfma_f32_16x16x32_bf16(
                    ah[mr], bl[nc], acc[mr][nc], 0, 0, 0);
                acc[mr][nc] = __builtin_amdgcn_mfma_f32_16x16x32_bf16(
                    al[mr], bh[nc], acc[mr][nc], 0, 0, 0);
            }
        __syncthreads();
    }

    // ---- epilogue: acc -> LDS f32 [128][68] -> bf16 short8 stores ----
    const float* bs = (colBase < G3) ? bias0 : bias1;
    const int bcol = (colBase < G3) ? colBase : (colBase - G3);
    float* ldsf = (float*)smem;           // 128*68*4 = 34816 B <= 40960
    #pragma unroll
    for (int half = 0; half < 2; ++half) {
        __syncthreads();
        if ((wid & 1) == half) {
            #pragma unroll
            for (int nc = 0; nc < 4; ++nc) {
                const int c = nc * 16 + rlane;
                const float bv = bs[bcol + half * 64 + c];
                #pragma unroll
                for (int mr = 0; mr < 4; ++mr)
                    #pragma unroll
                    for (int r = 0; r < 4; ++r)
                        ldsf[(wrow + mr * 16 + kgrp * 4 + r) * 68 + c] =
                            acc[mr][nc][r] + bv;
            }
        }
        __syncthreads();
        const int row = tid >> 1;
        const int ch  = (tid & 1) * 32;
        if (rowBase + row < M) {
            short* cp = C + (size_t)(rowBase + row) * NPROJ
                          + colBase + half * 64 + ch;
            #pragma unroll
            for (int i = 0; i < 4; ++i) {
                bf16x8 o;
                #pragma unroll
                for (int j = 0; j < 8; ++j)
                    o[j] = f2bf(ldsf[row * 68 + ch + i * 8 + j]);
                *(bf16x8*)(cp + i * 8) = o;
            }
        }
    }
}

// ---------------------------------------------------------------------------
// Single-block counting sort for BOTH length arrays.
// ---------------------------------------------------------------------------
__global__ __launch_bounds__(256) void sort_all(
    const int* __restrict__ len1, int* __restrict__ order1,
    const int* __restrict__ len2, int* __restrict__ order2)
{
    __shared__ int hist[65];
    const int tid = threadIdx.x;

    for (int i = tid; i < 65; i += 256) hist[i] = 0;
    __syncthreads();
    for (int i = tid; i < NSENT; i += 256) atomicAdd(&hist[len1[i]], 1);
    __syncthreads();
    if (tid == 0) {
        int acc = 0;
        for (int l = 1; l <= WW; ++l) { int c = hist[l]; hist[l] = acc; acc += c; }
    }
    __syncthreads();
    for (int i = tid; i < NSENT; i += 256) {
        int pos = atomicAdd(&hist[len1[i]], 1);
        order1[pos] = i;
    }
    __syncthreads();
    for (int i = tid; i < 65; i += 256) hist[i] = 0;
    __syncthreads();
    for (int i = tid; i < NREV; i += 256) atomicAdd(&hist[len2[i]], 1);
    __syncthreads();
    if (tid == 0) {
        int acc = 0;
        for (int l = 1; l <= SS; ++l) { int c = hist[l]; hist[l] = acc; acc += c; }
    }
    __syncthreads();
    for (int i = tid; i < NREV; i += 256) {
        int pos = atomicAdd(&hist[len2[i]], 1);
        order2[pos] = i;
    }
}

// ---------------------------------------------------------------------------
// MFMA GRU scan, single-bf16 h recurrence, BF16 table gathers with RAW-SHORT
// prefetch (bf2f deferred to the gate so loads stay outstanding across
// 2 steps — round-19's in-fetch conversion collapsed the prefetch depth).
// Structure otherwise = round-18 proven.
// ---------------------------------------------------------------------------
template<bool WORD, int TMAX>
__global__ __launch_bounds__(512, 2) void gru_mfma(
    const short* __restrict__ table,    // [*, 768] BF16 projected table
    const int*   __restrict__ tokens,
    const int*   __restrict__ lengths,
    const int*   __restrict__ order,
    const float* __restrict__ Whh_f, const float* __restrict__ Whh_b,
    const float* __restrict__ bhh_f, const float* __restrict__ bhh_b,
    float* __restrict__ hout_f, float* __restrict__ hout_b,
    int numSeq, int numTiles)
{
    const int dir  = (blockIdx.x >= numTiles) ? 1 : 0;
    const int rawt = dir ? (blockIdx.x - numTiles) : blockIdx.x;
    const int tile = numTiles - 1 - rawt;      // longest tiles first
    const int base = tile * 16;
    const int tid  = threadIdx.x;              // 0..511
    const int lane = tid & 63;
    const int wid  = tid >> 6;                 // 0..7
    const int rlane = lane & 15;
    const int kgrp  = lane >> 4;               // 0..3
    const int e = wid * 16 + rlane;            // this lane's gate element

    __shared__ __align__(16) short sh_hi[2][16][136];
    __shared__ int sh_len[16];
    __shared__ int sh_ord[16];
    __shared__ int sh_tok[WORD ? 16 * WW : 1];
    __shared__ int sh_maxlen;

    const float* Whh = dir ? Whh_b : Whh_f;
    const float* bhh = dir ? bhh_b : bhh_f;
    bf16x8 Bhi[3][4], Blo[3][4];
    float bb[3];
    #pragma unroll
    for (int nt = 0; nt < 3; ++nt) {
        const int cb = nt * HDIM + wid * 16;
        const float* wrow = Whh + (size_t)(cb + rlane) * HDIM;
        bb[nt] = bhh[cb + rlane];
        #pragma unroll
        for (int kc = 0; kc < 4; ++kc) {
            const float* wp = wrow + kc * 32 + kgrp * 8;
            float4 w0 = *(const float4*)wp;
            float4 w1 = *(const float4*)(wp + 4);
            float wv[8] = {w0.x, w0.y, w0.z, w0.w, w1.x, w1.y, w1.z, w1.w};
            #pragma unroll
            for (int j = 0; j < 8; ++j) {
                short hi = f2bf_t(wv[j]);
                Bhi[nt][kc][j] = hi;
                Blo[nt][kc][j] = f2bf(wv[j] - bf2f(hi));
            }
        }
    }

    if (tid < 16) {
        int pos = base + tid;
        int seq = (pos < numSeq) ? order[pos] : -1;
        sh_ord[tid] = seq;
        sh_len[tid] = (seq >= 0) ? lengths[seq] : 0;
    }
    __syncthreads();
    if (WORD) {
        for (int f = tid; f < 16 * WW; f += 512) {
            int s = f >> 6;
            int seq = sh_ord[s];
            sh_tok[f] = (seq >= 0) ? tokens[(size_t)seq * WW + (f & 63)] : 0;
        }
    }
    for (int u = tid; u < 2 * 16 * 136; u += 512)
        ((short*)sh_hi)[u] = 0;
    if (tid == 0) {
        int m = 0;
        for (int s = 0; s < 16; ++s) m = max(m, sh_len[s]);
        sh_maxlen = m;
    }
    int lens[4], ords[4];
    #pragma unroll
    for (int j = 0; j < 4; ++j) {
        lens[j] = sh_len[4 * kgrp + j];
        ords[j] = sh_ord[4 * kgrp + j];
    }
    __syncthreads();
    const int maxlen = sh_maxlen;

    // Raw-short gather: NO conversion here (keeps loads outstanding).
    auto fetch_xg = [&](int t, short* fr, short* fz, short* fn) {
        #pragma unroll
        for (int j = 0; j < 4; ++j) {
            fr[j] = 0; fz[j] = 0; fn[j] = 0;
            if (t < lens[j]) {
                int tt = dir ? (lens[j] - 1 - t) : t;
                size_t row;
                if (WORD) row = (size_t)sh_tok[(4 * kgrp + j) * WW + tt];
                else      row = (size_t)ords[j] * TMAX + tt;
                const short* xg = table + row * NPROJ + dir * G3 + e;
                fr[j] = xg[0];
                fz[j] = xg[HDIM];
                fn[j] = xg[2 * HDIM];
            }
        }
    };

    float hold[4] = {0.f, 0.f, 0.f, 0.f};
    short pAr[4], pAz[4], pAn[4];   // xg for even steps (raw bf16)
    short pBr[4], pBz[4], pBn[4];   // xg for odd steps
    fetch_xg(0, pAr, pAz, pAn);
    fetch_xg(1, pBr, pBz, pBn);

#define GRU_STEP(T, PR, PZ, PN)                                               \
    {                                                                         \
        const int cur = (T) & 1, nxt = cur ^ 1;                               \
        bf16x8 ah[4];                                                         \
        _Pragma("unroll")                                                     \
        for (int kc = 0; kc < 4; ++kc)                                        \
            ah[kc] = *(const bf16x8*)&sh_hi[cur][rlane][kc * 32 + kgrp * 8];  \
        f32x4 acc[3];                                                         \
        _Pragma("unroll")                                                     \
        for (int nt = 0; nt < 3; ++nt) {                                      \
            acc[nt] = {0.f, 0.f, 0.f, 0.f};                                   \
            _Pragma("unroll")                                                 \
            for (int kc = 0; kc < 4; ++kc)                                    \
                acc[nt] = __builtin_amdgcn_mfma_f32_16x16x32_bf16(            \
                    ah[kc], Bhi[nt][kc], acc[nt], 0, 0, 0);                   \
            _Pragma("unroll")                                                 \
            for (int kc = 0; kc < 4; ++kc)                                    \
                acc[nt] = __builtin_amdgcn_mfma_f32_16x16x32_bf16(            \
                    ah[kc], Blo[nt][kc], acc[nt], 0, 0, 0);                   \
        }                                                                     \
        _Pragma("unroll")                                                     \
        for (int j = 0; j < 4; ++j) {                                         \
            if ((T) < lens[j]) {                                              \
                float hgr = acc[0][j] + bb[0];                                \
                float hgz = acc[1][j] + bb[1];                                \
                float hgn = acc[2][j] + bb[2];                                \
                float rg = fsigmoid(bf2f(PR[j]) + hgr);                       \
                float zg = fsigmoid(bf2f(PZ[j]) + hgz);                       \
                float ng = ftanh(bf2f(PN[j]) + rg * hgn);                     \
                hold[j] = (1.f - zg) * ng + zg * hold[j];                     \
            }                                                                 \
        }                                                                     \
        fetch_xg((T) + 2, PR, PZ, PN);                                        \
        _Pragma("unroll")                                                     \
        for (int j = 0; j < 4; ++j) {                                         \
            const int s = 4 * kgrp + j;                                       \
            sh_hi[nxt][s][e] = f2bf(hold[j]);                                 \
        }                                                                     \
        __syncthreads();                                                      \
    }

    int t = 0;
    for (; t + 1 < maxlen; t += 2) {
        GRU_STEP(t,     pAr, pAz, pAn);
        GRU_STEP(t + 1, pBr, pBz, pBn);
    }
    if (t < maxlen) {
        GRU_STEP(t, pAr, pAz, pAn);
    }
#undef GRU_STEP

    float* hout = dir ? hout_b : hout_f;
    #pragma unroll
    for (int j = 0; j < 4; ++j) {
        if (ords[j] >= 0)
            hout[(size_t)ords[j] * HDIM + e] = hold[j];
    }
}

// ---------------------------------------------------------------------------
// Head + mean
// ---------------------------------------------------------------------------
__global__ __launch_bounds__(64) void head_kernel(
    const float* __restrict__ hsf, const float* __restrict__ hsb,
    const float* __restrict__ fc1_w, const float* __restrict__ fc1_b,
    const float* __restrict__ fc2_w, const float* __restrict__ fc2_b,
    float* __restrict__ out)
{
    const int br = blockIdx.x;
    const int j = threadIdx.x;
    __shared__ float rev[HDIM];
    for (int ee = j; ee < HDIM; ee += 64)
        rev[ee] = 0.5f * (hsf[(size_t)br * HDIM + ee] + hsb[(size_t)br * HDIM + ee]);
    __syncthreads();
    float acc = 0.f;
    #pragma unroll
    for (int k = 0; k < HDIM; ++k)
        acc = fmaf(fc1_w[(size_t)j * HDIM + k], rev[k], acc);
    acc += fc1_b[j];
    const float alpha = 1.6732632423543772f;
    const float scale = 1.0507009873554805f;
    float h1 = scale * (acc > 0.f ? acc : alpha * (expf(acc) - 1.f));
    float contrib = h1 * fc2_w[j];
    #pragma unroll
    for (int off = 32; off > 0; off >>= 1)
        contrib += __shfl_down(contrib, off);
    if (j == 0) out[16 + br] = contrib + fc2_b[0];
}

__global__ void mean_kernel(float* __restrict__ out)
{
    int b = threadIdx.x;
    if (b < BB) {
        float s = 0.f;
        for (int r = 0; r < RR; ++r) s += out[16 + b * RR + r];
        out[b] = s / (float)RR;
    }
}

// ---------------------------------------------------------------------------
// Launch
// ---------------------------------------------------------------------------
extern "C" void kernel_launch(void* const* d_in, const int* in_sizes, int n_in,
                              void* d_out, int out_size, void* d_ws, size_t ws_size,
                              hipStream_t stream)
{
    const int*   inputs       = (const int*)d_in[0];
    const int*   sent_lengths = (const int*)d_in[1];
    const int*   sent_counts  = (const int*)d_in[2];
    const float* embed   = (const float*)d_in[3];
    const float* wWih_f  = (const float*)d_in[4];
    const float* wWhh_f  = (const float*)d_in[5];
    const float* wbih_f  = (const float*)d_in[6];
    const float* wbhh_f  = (const float*)d_in[7];
    const float* wWih_b  = (const float*)d_in[8];
    const float* wWhh_b  = (const float*)d_in[9];
    const float* wbih_b  = (const float*)d_in[10];
    const float* wbhh_b  = (const float*)d_in[11];
    const float* sWih_f  = (const float*)d_in[12];
    const float* sWhh_f  = (const float*)d_in[13];
    const float* sbih_f  = (const float*)d_in[14];
    const float* sbhh_f  = (const float*)d_in[15];
    const float* sWih_b  = (const float*)d_in[16];
    const float* sWhh_b  = (const float*)d_in[17];
    const float* sbih_b  = (const float*)d_in[18];
    const float* sbhh_b  = (const float*)d_in[19];
    const float* fc1_w   = (const float*)d_in[20];
    const float* fc1_b   = (const float*)d_in[21];
    const float* fc2_w   = (const float*)d_in[22];
    const float* fc2_b   = (const float*)d_in[23];

    float* ws = (float*)d_ws;
    const size_t projT_elems = (size_t)VOCAB * NPROJ;      // shorts
    const size_t xgs_elems   = (size_t)NSENT * NPROJ;      // shorts
    const size_t h_elems     = (size_t)NSENT * HDIM;       // f32
    const size_t hs_elems    = (size_t)NREV * HDIM;        // f32
    float* hf    = ws;
    float* hb    = hf + h_elems;
    float* hsf   = hb + h_elems;
    float* hsb   = hsf + hs_elems;
    int* order1  = (int*)(hsb + hs_elems);         // [NSENT]
    int* order2  = order1 + NSENT;                 // [NREV]
    short* projT = (short*)(order2 + NREV);        // [VOCAB*768] bf16
    short* xgs   = projT + projT_elems;            // [NSENT*768] bf16
    short* Bw_hi = xgs + xgs_elems;                // [768*224]
    short* Bw_lo = Bw_hi + 768 * 224;
    short* Sw_hi = Bw_lo + 768 * 224;              // [768*128]
    short* Sw_lo = Sw_hi + 768 * 128;

    size_t need = (2*h_elems + 2*hs_elems) * sizeof(float)
                + (NSENT + NREV) * sizeof(int)
                + (projT_elems + xgs_elems
                   + (size_t)(2 * 768 * 224 + 2 * 768 * 128)) * sizeof(short);
    if (ws_size < need) return;

    // 0) counting sort + merged weight-blob preconversion
    sort_all<<<1, 256, 0, stream>>>(sent_lengths, order1, sent_counts, order2);
    {
        int ng = 2 * NG1 + 2 * NG2;
        preconv_all<<<(ng + 255) / 256, 256, 0, stream>>>(
            wWih_f, wWih_b, sWih_f, sWih_b, Bw_hi, Bw_lo, Sw_hi, Sw_lo);
    }

    // 1) projected-embedding table -> BF16 (grid x=rt for L2-friendly A reads)
    {
        dim3 grid((VOCAB + 127) / 128, NPROJ / 128);    // 391 x 6
        gemm_v6<EDIM, 224, false><<<grid, 256, 0, stream>>>(
            embed, nullptr, VOCAB, Bw_hi, Bw_lo, wbih_f, wbih_b, projT);
    }
    // 2) word-level BiGRU last-h (bf16-table scan, raw-short prefetch)
    {
        int numTiles = NSENT / 16;                      // 200
        gru_mfma<true, WW><<<2 * numTiles, 512, 0, stream>>>(
            projT, inputs, sent_lengths, order1,
            wWhh_f, wWhh_b, wbhh_f, wbhh_b,
            hf, hb, NSENT, numTiles);
    }
    // 3) sentence-level input projections -> BF16
    {
        dim3 grid((NSENT + 127) / 128, NPROJ / 128);    // 25 x 6
        gemm_v6<HDIM, HDIM, true><<<grid, 256, 0, stream>>>(
            hf, hb, NSENT, Sw_hi, Sw_lo, sbih_f, sbih_b, xgs);
    }
    // 4) sentence-level BiGRU last-h
    {
        int numTiles = NREV / 16;                       // 10
        gru_mfma<false, SS><<<2 * numTiles, 512, 0, stream>>>(
            xgs, nullptr, sent_counts, order2,
            sWhh_f, sWhh_b, sbhh_f, sbhh_b,
            hsf, hsb, NREV, numTiles);
    }
    // 5) FC head -> r_stars, then p_stars
    head_kernel<<<NREV, 64, 0, stream>>>(hsf, hsb, fc1_w, fc1_b, fc2_w, fc2_b,
                                         (float*)d_out);
    mean_kernel<<<1, 64, 0, stream>>>((float*)d_out);
}

// Round 21
// 276.863 us; speedup vs baseline: 1.2299x; 1.0585x over previous
//
#include <hip/hip_runtime.h>
#include <hip/hip_bf16.h>
#include <cstddef>

// ---------------------------------------------------------------------------
// Problem dims
// ---------------------------------------------------------------------------
#define VOCAB 50000
#define EDIM  200
#define HDIM  128
#define BB 16
#define RR 10
#define SS 20
#define WW 64
#define NSENT (BB*RR*SS)   // 3200 word-level sequences
#define NREV  (BB*RR)      // 160 sentence-level sequences
#define G3    (3*HDIM)     // 384 gate rows per direction
#define NPROJ (2*G3)       // 768

// ---------------------------------------------------------------------------
// bf16 + fast-math helpers
// ---------------------------------------------------------------------------
static __device__ __forceinline__ short f2bf(float f) {    // RNE
    union { float f; unsigned u; } v; v.f = f;
    unsigned r = v.u + 0x7FFFu + ((v.u >> 16) & 1u);
    return (short)(r >> 16);
}
static __device__ __forceinline__ short f2bf_t(float f) {  // truncate
    union { float f; unsigned u; } v; v.f = f;
    return (short)(v.u >> 16);
}
static __device__ __forceinline__ float bf2f(short s) {
    union { unsigned u; float f; } v;
    v.u = ((unsigned)(unsigned short)s) << 16;
    return v.f;
}
static __device__ __forceinline__ float u2f(unsigned uu) { // zero-extended bf16
    union { unsigned u; float f; } v;
    v.u = uu << 16;
    return v.f;
}
static __device__ __forceinline__ float frcp(float x) {
    return __builtin_amdgcn_rcpf(x);
}
static __device__ __forceinline__ float fsigmoid(float x) {
    return frcp(1.f + __expf(-x));
}
static __device__ __forceinline__ float ftanh(float x) {
    float y = __expf(-2.f * fabsf(x));
    float t = (1.f - y) * frcp(1.f + y);
    return copysignf(t, x);
}

using bf16x8 = __attribute__((ext_vector_type(8))) short;
using f32x4  = __attribute__((ext_vector_type(4))) float;

// ---------------------------------------------------------------------------
// preconv_all: ONE launch converting all 4 weight matrices to split-bf16
// blobs (wWih_f/b: 200->224 pad; sWih_f/b: 128).
// ---------------------------------------------------------------------------
#define NG1 (384 * 224 / 8)   // 10752
#define NG2 (384 * 128 / 8)   // 6144

__global__ __launch_bounds__(256) void preconv_all(
    const float* __restrict__ wWih_f, const float* __restrict__ wWih_b,
    const float* __restrict__ sWih_f, const float* __restrict__ sWih_b,
    short* __restrict__ Bw_hi, short* __restrict__ Bw_lo,
    short* __restrict__ Sw_hi, short* __restrict__ Sw_lo)
{
    int g = blockIdx.x * 256 + threadIdx.x;
    const float* src; short* hi; short* lo; int KREAL, KPAD;
    if (g < NG1) {
        src = wWih_f; hi = Bw_hi; lo = Bw_lo; KREAL = 200; KPAD = 224;
    } else if (g < 2 * NG1) {
        g -= NG1;
        src = wWih_b; hi = Bw_hi + 384 * 224; lo = Bw_lo + 384 * 224;
        KREAL = 200; KPAD = 224;
    } else if (g < 2 * NG1 + NG2) {
        g -= 2 * NG1;
        src = sWih_f; hi = Sw_hi; lo = Sw_lo; KREAL = 128; KPAD = 128;
    } else if (g < 2 * NG1 + 2 * NG2) {
        g -= 2 * NG1 + NG2;
        src = sWih_b; hi = Sw_hi + 384 * 128; lo = Sw_lo + 384 * 128;
        KREAL = 128; KPAD = 128;
    } else return;

    int row = g / (KPAD / 8);
    int k   = (g % (KPAD / 8)) * 8;
    float v[8];
    if (k < KREAL) {
        const float* p = src + (size_t)row * KREAL + k;
        float4 a = *(const float4*)p;
        float4 b = *(const float4*)(p + 4);
        v[0]=a.x; v[1]=a.y; v[2]=a.z; v[3]=a.w;
        v[4]=b.x; v[5]=b.y; v[6]=b.z; v[7]=b.w;
    } else {
        #pragma unroll
        for (int j = 0; j < 8; ++j) v[j] = 0.f;
    }
    bf16x8 h, l;
    #pragma unroll
    for (int j = 0; j < 8; ++j) {
        short t = f2bf_t(v[j]);
        h[j] = t;
        l[j] = f2bf(v[j] - bf2f(t));
    }
    *(bf16x8*)&hi[(size_t)row * KPAD + k] = h;
    *(bf16x8*)&lo[(size_t)row * KPAD + k] = l;
}

// ---------------------------------------------------------------------------
// gemm_v6: split-bf16 MFMA GEMM, XCD-friendly grid, coalesced LDS-staged
// epilogue writing the table as BF16 (RNE).
// ---------------------------------------------------------------------------
template<int KREAL, int KPAD, bool AVG>
__global__ __launch_bounds__(256, 2) void gemm_v6(
    const float* __restrict__ A0, const float* __restrict__ A1, int M,
    const short* __restrict__ Bhi_g, const short* __restrict__ Blo_g,
    const float* __restrict__ bias0, const float* __restrict__ bias1,
    short* __restrict__ C)
{
    const int rt = blockIdx.x;
    const int ct = blockIdx.y;
    const int tid = threadIdx.x;
    const int lane = tid & 63;
    const int wid  = tid >> 6;
    const int rlane = lane & 15;
    const int kgrp  = lane >> 4;

    const int rowBase = rt * 128;
    const int colBase = ct * 128;

    __shared__ __align__(16) short smem[4 * 128 * 40];   // 40960 B
    short (*Ahi)[40] = (short(*)[40])(smem);
    short (*Alo)[40] = (short(*)[40])(smem + 5120);
    short (*Bhi)[40] = (short(*)[40])(smem + 10240);
    short (*Blo)[40] = (short(*)[40])(smem + 15360);

    const int wrow = (wid >> 1) * 64;
    const int wcol = (wid & 1) * 64;

    f32x4 acc[4][4];
    #pragma unroll
    for (int i = 0; i < 4; ++i)
        #pragma unroll
        for (int j = 0; j < 4; ++j) acc[i][j] = {0.f, 0.f, 0.f, 0.f};

    const int srow = tid >> 1;
    const int skh  = (tid & 1) << 4;
    const int grow = rowBase + srow;
    const size_t brow = (size_t)(colBase + srow) * KPAD;

    for (int k0 = 0; k0 < KPAD; k0 += 32) {
        {
            float v[16];
            #pragma unroll
            for (int i = 0; i < 4; ++i) {
                const int k = k0 + skh + i * 4;
                float4 x = {0.f, 0.f, 0.f, 0.f};
                if (grow < M && k + 3 < KREAL) {
                    x = *(const float4*)&A0[(size_t)grow * KREAL + k];
                    if (AVG) {
                        float4 y = *(const float4*)&A1[(size_t)grow * KREAL + k];
                        x.x = 0.5f * (x.x + y.x); x.y = 0.5f * (x.y + y.y);
                        x.z = 0.5f * (x.z + y.z); x.w = 0.5f * (x.w + y.w);
                    }
                }
                v[4*i+0] = x.x; v[4*i+1] = x.y; v[4*i+2] = x.z; v[4*i+3] = x.w;
            }
            bf16x8 h0, h1, l0, l1;
            #pragma unroll
            for (int i = 0; i < 8; ++i) {
                short a = f2bf_t(v[i]);
                h0[i] = a; l0[i] = f2bf(v[i] - bf2f(a));
                short b = f2bf_t(v[i + 8]);
                h1[i] = b; l1[i] = f2bf(v[i + 8] - bf2f(b));
            }
            *(bf16x8*)&Ahi[srow][skh]     = h0;
            *(bf16x8*)&Ahi[srow][skh + 8] = h1;
            *(bf16x8*)&Alo[srow][skh]     = l0;
            *(bf16x8*)&Alo[srow][skh + 8] = l1;
        }
        *(bf16x8*)&Bhi[srow][skh]     = *(const bf16x8*)&Bhi_g[brow + k0 + skh];
        *(bf16x8*)&Bhi[srow][skh + 8] = *(const bf16x8*)&Bhi_g[brow + k0 + skh + 8];
        *(bf16x8*)&Blo[srow][skh]     = *(const bf16x8*)&Blo_g[brow + k0 + skh];
        *(bf16x8*)&Blo[srow][skh + 8] = *(const bf16x8*)&Blo_g[brow + k0 + skh + 8];
        __syncthreads();
        bf16x8 ah[4], al[4], bh[4], bl[4];
        #pragma unroll
        for (int mr = 0; mr < 4; ++mr) {
            ah[mr] = *(const bf16x8*)&Ahi[wrow + mr * 16 + rlane][kgrp * 8];
            al[mr] = *(const bf16x8*)&Alo[wrow + mr * 16 + rlane][kgrp * 8];
        }
        #pragma unroll
        for (int nc = 0; nc < 4; ++nc) {
            bh[nc] = *(const bf16x8*)&Bhi[wcol + nc * 16 + rlane][kgrp * 8];
            bl[nc] = *(const bf16x8*)&Blo[wcol + nc * 16 + rlane][kgrp * 8];
        }
        #pragma unroll
        for (int mr = 0; mr < 4; ++mr)
            #pragma unroll
            for (int nc = 0; nc < 4; ++nc) {
                acc[mr][nc] = __builtin_amdgcn_mfma_f32_16x16x32_bf16(
                    ah[mr], bh[nc], acc[mr][nc], 0, 0, 0);
                acc[mr][nc] = __builtin_amdgcn_mfma_f32_16x16x32_bf16(
                    ah[mr], bl[nc], acc[mr][nc], 0, 0, 0);
                acc[mr][nc] = __builtin_amdgcn_mfma_f32_16x16x32_bf16(
                    al[mr], bh[nc], acc[mr][nc], 0, 0, 0);
            }
        __syncthreads();
    }

    // ---- epilogue: acc -> LDS f32 [128][68] -> bf16 short8 stores ----
    const float* bs = (colBase < G3) ? bias0 : bias1;
    const int bcol = (colBase < G3) ? colBase : (colBase - G3);
    float* ldsf = (float*)smem;           // 128*68*4 = 34816 B <= 40960
    #pragma unroll
    for (int half = 0; half < 2; ++half) {
        __syncthreads();
        if ((wid & 1) == half) {
            #pragma unroll
            for (int nc = 0; nc < 4; ++nc) {
                const int c = nc * 16 + rlane;
                const float bv = bs[bcol + half * 64 + c];
                #pragma unroll
                for (int mr = 0; mr < 4; ++mr)
                    #pragma unroll
                    for (int r = 0; r < 4; ++r)
                        ldsf[(wrow + mr * 16 + kgrp * 4 + r) * 68 + c] =
                            acc[mr][nc][r] + bv;
            }
        }
        __syncthreads();
        const int row = tid >> 1;
        const int ch  = (tid & 1) * 32;
        if (rowBase + row < M) {
            short* cp = C + (size_t)(rowBase + row) * NPROJ
                          + colBase + half * 64 + ch;
            #pragma unroll
            for (int i = 0; i < 4; ++i) {
                bf16x8 o;
                #pragma unroll
                for (int j = 0; j < 8; ++j)
                    o[j] = f2bf(ldsf[row * 68 + ch + i * 8 + j]);
                *(bf16x8*)(cp + i * 8) = o;
            }
        }
    }
}

// ---------------------------------------------------------------------------
// Single-block counting sort for BOTH length arrays.
// ---------------------------------------------------------------------------
__global__ __launch_bounds__(256) void sort_all(
    const int* __restrict__ len1, int* __restrict__ order1,
    const int* __restrict__ len2, int* __restrict__ order2)
{
    __shared__ int hist[65];
    const int tid = threadIdx.x;

    for (int i = tid; i < 65; i += 256) hist[i] = 0;
    __syncthreads();
    for (int i = tid; i < NSENT; i += 256) atomicAdd(&hist[len1[i]], 1);
    __syncthreads();
    if (tid == 0) {
        int acc = 0;
        for (int l = 1; l <= WW; ++l) { int c = hist[l]; hist[l] = acc; acc += c; }
    }
    __syncthreads();
    for (int i = tid; i < NSENT; i += 256) {
        int pos = atomicAdd(&hist[len1[i]], 1);
        order1[pos] = i;
    }
    __syncthreads();
    for (int i = tid; i < 65; i += 256) hist[i] = 0;
    __syncthreads();
    for (int i = tid; i < NREV; i += 256) atomicAdd(&hist[len2[i]], 1);
    __syncthreads();
    if (tid == 0) {
        int acc = 0;
        for (int l = 1; l <= SS; ++l) { int c = hist[l]; hist[l] = acc; acc += c; }
    }
    __syncthreads();
    for (int i = tid; i < NREV; i += 256) {
        int pos = atomicAdd(&hist[len2[i]], 1);
        order2[pos] = i;
    }
}

// ---------------------------------------------------------------------------
// MFMA GRU scan, single-bf16 h recurrence, BF16 table gathers prefetched
// into 32-BIT unsigned regs (global_load_ushort zero-extends: full-register
// write, no d16 partial-write dependency -> loads stay outstanding across
// 2 steps). bf16->f32 at the gate is one shift. Structure = round-18.
// ---------------------------------------------------------------------------
template<bool WORD, int TMAX>
__global__ __launch_bounds__(512, 2) void gru_mfma(
    const unsigned short* __restrict__ table,   // [*, 768] BF16 table
    const int*   __restrict__ tokens,
    const int*   __restrict__ lengths,
    const int*   __restrict__ order,
    const float* __restrict__ Whh_f, const float* __restrict__ Whh_b,
    const float* __restrict__ bhh_f, const float* __restrict__ bhh_b,
    float* __restrict__ hout_f, float* __restrict__ hout_b,
    int numSeq, int numTiles)
{
    const int dir  = (blockIdx.x >= numTiles) ? 1 : 0;
    const int rawt = dir ? (blockIdx.x - numTiles) : blockIdx.x;
    const int tile = numTiles - 1 - rawt;      // longest tiles first
    const int base = tile * 16;
    const int tid  = threadIdx.x;              // 0..511
    const int lane = tid & 63;
    const int wid  = tid >> 6;                 // 0..7
    const int rlane = lane & 15;
    const int kgrp  = lane >> 4;               // 0..3
    const int e = wid * 16 + rlane;            // this lane's gate element

    __shared__ __align__(16) short sh_hi[2][16][136];
    __shared__ int sh_len[16];
    __shared__ int sh_ord[16];
    __shared__ int sh_tok[WORD ? 16 * WW : 1];
    __shared__ int sh_maxlen;

    const float* Whh = dir ? Whh_b : Whh_f;
    const float* bhh = dir ? bhh_b : bhh_f;
    bf16x8 Bhi[3][4], Blo[3][4];
    float bb[3];
    #pragma unroll
    for (int nt = 0; nt < 3; ++nt) {
        const int cb = nt * HDIM + wid * 16;
        const float* wrow = Whh + (size_t)(cb + rlane) * HDIM;
        bb[nt] = bhh[cb + rlane];
        #pragma unroll
        for (int kc = 0; kc < 4; ++kc) {
            const float* wp = wrow + kc * 32 + kgrp * 8;
            float4 w0 = *(const float4*)wp;
            float4 w1 = *(const float4*)(wp + 4);
            float wv[8] = {w0.x, w0.y, w0.z, w0.w, w1.x, w1.y, w1.z, w1.w};
            #pragma unroll
            for (int j = 0; j < 8; ++j) {
                short hi = f2bf_t(wv[j]);
                Bhi[nt][kc][j] = hi;
                Blo[nt][kc][j] = f2bf(wv[j] - bf2f(hi));
            }
        }
    }

    if (tid < 16) {
        int pos = base + tid;
        int seq = (pos < numSeq) ? order[pos] : -1;
        sh_ord[tid] = seq;
        sh_len[tid] = (seq >= 0) ? lengths[seq] : 0;
    }
    __syncthreads();
    if (WORD) {
        for (int f = tid; f < 16 * WW; f += 512) {
            int s = f >> 6;
            int seq = sh_ord[s];
            sh_tok[f] = (seq >= 0) ? tokens[(size_t)seq * WW + (f & 63)] : 0;
        }
    }
    for (int u = tid; u < 2 * 16 * 136; u += 512)
        ((short*)sh_hi)[u] = 0;
    if (tid == 0) {
        int m = 0;
        for (int s = 0; s < 16; ++s) m = max(m, sh_len[s]);
        sh_maxlen = m;
    }
    int lens[4], ords[4];
    #pragma unroll
    for (int j = 0; j < 4; ++j) {
        lens[j] = sh_len[4 * kgrp + j];
        ords[j] = sh_ord[4 * kgrp + j];
    }
    __syncthreads();
    const int maxlen = sh_maxlen;

    // Gather into 32-bit regs (zero-extending ushort loads, full-reg writes).
    auto fetch_xg = [&](int t, unsigned* fr, unsigned* fz, unsigned* fn) {
        #pragma unroll
        for (int j = 0; j < 4; ++j) {
            fr[j] = 0; fz[j] = 0; fn[j] = 0;
            if (t < lens[j]) {
                int tt = dir ? (lens[j] - 1 - t) : t;
                size_t row;
                if (WORD) row = (size_t)sh_tok[(4 * kgrp + j) * WW + tt];
                else      row = (size_t)ords[j] * TMAX + tt;
                const unsigned short* xg = table + row * NPROJ + dir * G3 + e;
                fr[j] = (unsigned)xg[0];
                fz[j] = (unsigned)xg[HDIM];
                fn[j] = (unsigned)xg[2 * HDIM];
            }
        }
    };

    float hold[4] = {0.f, 0.f, 0.f, 0.f};
    unsigned pAr[4], pAz[4], pAn[4];   // xg for even steps (zext bf16)
    unsigned pBr[4], pBz[4], pBn[4];   // xg for odd steps
    fetch_xg(0, pAr, pAz, pAn);
    fetch_xg(1, pBr, pBz, pBn);

#define GRU_STEP(T, PR, PZ, PN)                                               \
    {                                                                         \
        const int cur = (T) & 1, nxt = cur ^ 1;                               \
        bf16x8 ah[4];                                                         \
        _Pragma("unroll")                                                     \
        for (int kc = 0; kc < 4; ++kc)                                        \
            ah[kc] = *(const bf16x8*)&sh_hi[cur][rlane][kc * 32 + kgrp * 8];  \
        f32x4 acc[3];                                                         \
        _Pragma("unroll")                                                     \
        for (int nt = 0; nt < 3; ++nt) {                                      \
            acc[nt] = {0.f, 0.f, 0.f, 0.f};                                   \
            _Pragma("unroll")                                                 \
            for (int kc = 0; kc < 4; ++kc)                                    \
                acc[nt] = __builtin_amdgcn_mfma_f32_16x16x32_bf16(            \
                    ah[kc], Bhi[nt][kc], acc[nt], 0, 0, 0);                   \
            _Pragma("unroll")                                                 \
            for (int kc = 0; kc < 4; ++kc)                                    \
                acc[nt] = __builtin_amdgcn_mfma_f32_16x16x32_bf16(            \
                    ah[kc], Blo[nt][kc], acc[nt], 0, 0, 0);                   \
        }                                                                     \
        _Pragma("unroll")                                                     \
        for (int j = 0; j < 4; ++j) {                                         \
            if ((T) < lens[j]) {                                              \
                float hgr = acc[0][j] + bb[0];                                \
                float hgz = acc[1][j] + bb[1];                                \
                float hgn = acc[2][j] + bb[2];                                \
                float rg = fsigmoid(u2f(PR[j]) + hgr);                        \
                float zg = fsigmoid(u2f(PZ[j]) + hgz);                        \
                float ng = ftanh(u2f(PN[j]) + rg * hgn);                      \
                hold[j] = (1.f - zg) * ng + zg * hold[j];                     \
            }                                                                 \
        }                                                                     \
        fetch_xg((T) + 2, PR, PZ, PN);                                        \
        _Pragma("unroll")                                                     \
        for (int j = 0; j < 4; ++j) {                                         \
            const int s = 4 * kgrp + j;                                       \
            sh_hi[nxt][s][e] = f2bf(hold[j]);                                 \
        }                                                                     \
        __syncthreads();                                                      \
    }

    int t = 0;
    for (; t + 1 < maxlen; t += 2) {
        GRU_STEP(t,     pAr, pAz, pAn);
        GRU_STEP(t + 1, pBr, pBz, pBn);
    }
    if (t < maxlen) {
        GRU_STEP(t, pAr, pAz, pAn);
    }
#undef GRU_STEP

    float* hout = dir ? hout_b : hout_f;
    #pragma unroll
    for (int j = 0; j < 4; ++j) {
        if (ords[j] >= 0)
            hout[(size_t)ords[j] * HDIM + e] = hold[j];
    }
}

// ---------------------------------------------------------------------------
// Head + mean
// ---------------------------------------------------------------------------
__global__ __launch_bounds__(64) void head_kernel(
    const float* __restrict__ hsf, const float* __restrict__ hsb,
    const float* __restrict__ fc1_w, const float* __restrict__ fc1_b,
    const float* __restrict__ fc2_w, const float* __restrict__ fc2_b,
    float* __restrict__ out)
{
    const int br = blockIdx.x;
    const int j = threadIdx.x;
    __shared__ float rev[HDIM];
    for (int ee = j; ee < HDIM; ee += 64)
        rev[ee] = 0.5f * (hsf[(size_t)br * HDIM + ee] + hsb[(size_t)br * HDIM + ee]);
    __syncthreads();
    float acc = 0.f;
    #pragma unroll
    for (int k = 0; k < HDIM; ++k)
        acc = fmaf(fc1_w[(size_t)j * HDIM + k], rev[k], acc);
    acc += fc1_b[j];
    const float alpha = 1.6732632423543772f;
    const float scale = 1.0507009873554805f;
    float h1 = scale * (acc > 0.f ? acc : alpha * (expf(acc) - 1.f));
    float contrib = h1 * fc2_w[j];
    #pragma unroll
    for (int off = 32; off > 0; off >>= 1)
        contrib += __shfl_down(contrib, off);
    if (j == 0) out[16 + br] = contrib + fc2_b[0];
}

__global__ void mean_kernel(float* __restrict__ out)
{
    int b = threadIdx.x;
    if (b < BB) {
        float s = 0.f;
        for (int r = 0; r < RR; ++r) s += out[16 + b * RR + r];
        out[b] = s / (float)RR;
    }
}

// ---------------------------------------------------------------------------
// Launch
// ---------------------------------------------------------------------------
extern "C" void kernel_launch(void* const* d_in, const int* in_sizes, int n_in,
                              void* d_out, int out_size, void* d_ws, size_t ws_size,
                              hipStream_t stream)
{
    const int*   inputs       = (const int*)d_in[0];
    const int*   sent_lengths = (const int*)d_in[1];
    const int*   sent_counts  = (const int*)d_in[2];
    const float* embed   = (const float*)d_in[3];
    const float* wWih_f  = (const float*)d_in[4];
    const float* wWhh_f  = (const float*)d_in[5];
    const float* wbih_f  = (const float*)d_in[6];
    const float* wbhh_f  = (const float*)d_in[7];
    const float* wWih_b  = (const float*)d_in[8];
    const float* wWhh_b  = (const float*)d_in[9];
    const float* wbih_b  = (const float*)d_in[10];
    const float* wbhh_b  = (const float*)d_in[11];
    const float* sWih_f  = (const float*)d_in[12];
    const float* sWhh_f  = (const float*)d_in[13];
    const float* sbih_f  = (const float*)d_in[14];
    const float* sbhh_f  = (const float*)d_in[15];
    const float* sWih_b  = (const float*)d_in[16];
    const float* sWhh_b  = (const float*)d_in[17];
    const float* sbih_b  = (const float*)d_in[18];
    const float* sbhh_b  = (const float*)d_in[19];
    const float* fc1_w   = (const float*)d_in[20];
    const float* fc1_b   = (const float*)d_in[21];
    const float* fc2_w   = (const float*)d_in[22];
    const float* fc2_b   = (const float*)d_in[23];

    float* ws = (float*)d_ws;
    const size_t projT_elems = (size_t)VOCAB * NPROJ;      // shorts
    const size_t xgs_elems   = (size_t)NSENT * NPROJ;      // shorts
    const size_t h_elems     = (size_t)NSENT * HDIM;       // f32
    const size_t hs_elems    = (size_t)NREV * HDIM;        // f32
    float* hf    = ws;
    float* hb    = hf + h_elems;
    float* hsf   = hb + h_elems;
    float* hsb   = hsf + hs_elems;
    int* order1  = (int*)(hsb + hs_elems);         // [NSENT]
    int* order2  = order1 + NSENT;                 // [NREV]
    short* projT = (short*)(order2 + NREV);        // [VOCAB*768] bf16
    short* xgs   = projT + projT_elems;            // [NSENT*768] bf16
    short* Bw_hi = xgs + xgs_elems;                // [768*224]
    short* Bw_lo = Bw_hi + 768 * 224;
    short* Sw_hi = Bw_lo + 768 * 224;              // [768*128]
    short* Sw_lo = Sw_hi + 768 * 128;

    size_t need = (2*h_elems + 2*hs_elems) * sizeof(float)
                + (NSENT + NREV) * sizeof(int)
                + (projT_elems + xgs_elems
                   + (size_t)(2 * 768 * 224 + 2 * 768 * 128)) * sizeof(short);
    if (ws_size < need) return;

    // 0) counting sort + merged weight-blob preconversion
    sort_all<<<1, 256, 0, stream>>>(sent_lengths, order1, sent_counts, order2);
    {
        int ng = 2 * NG1 + 2 * NG2;
        preconv_all<<<(ng + 255) / 256, 256, 0, stream>>>(
            wWih_f, wWih_b, sWih_f, sWih_b, Bw_hi, Bw_lo, Sw_hi, Sw_lo);
    }

    // 1) projected-embedding table -> BF16 (grid x=rt for L2-friendly A reads)
    {
        dim3 grid((VOCAB + 127) / 128, NPROJ / 128);    // 391 x 6
        gemm_v6<EDIM, 224, false><<<grid, 256, 0, stream>>>(
            embed, nullptr, VOCAB, Bw_hi, Bw_lo, wbih_f, wbih_b, projT);
    }
    // 2) word-level BiGRU last-h (bf16-table scan, zext-dword prefetch)
    {
        int numTiles = NSENT / 16;                      // 200
        gru_mfma<true, WW><<<2 * numTiles, 512, 0, stream>>>(
            (const unsigned short*)projT, inputs, sent_lengths, order1,
            wWhh_f, wWhh_b, wbhh_f, wbhh_b,
            hf, hb, NSENT, numTiles);
    }
    // 3) sentence-level input projections -> BF16
    {
        dim3 grid((NSENT + 127) / 128, NPROJ / 128);    // 25 x 6
        gemm_v6<HDIM, HDIM, true><<<grid, 256, 0, stream>>>(
            hf, hb, NSENT, Sw_hi, Sw_lo, sbih_f, sbih_b, xgs);
    }
    // 4) sentence-level BiGRU last-h
    {
        int numTiles = NREV / 16;                       // 10
        gru_mfma<false, SS><<<2 * numTiles, 512, 0, stream>>>(
            (const unsigned short*)xgs, nullptr, sent_counts, order2,
            sWhh_f, sWhh_b, sbhh_f, sbhh_b,
            hsf, hsb, NREV, numTiles);
    }
    // 5) FC head -> r_stars, then p_stars
    head_kernel<<<NREV, 64, 0, stream>>>(hsf, hsb, fc1_w, fc1_b, fc2_w, fc2_b,
                                         (float*)d_out);
    mean_kernel<<<1, 64, 0, stream>>>((float*)d_out);
}

// Round 22
// 265.974 us; speedup vs baseline: 1.2802x; 1.0409x over previous
//
#include <hip/hip_runtime.h>
#include <hip/hip_bf16.h>
#include <cstddef>

// ---------------------------------------------------------------------------
// Problem dims
// ---------------------------------------------------------------------------
#define VOCAB 50000
#define EDIM  200
#define HDIM  128
#define BB 16
#define RR 10
#define SS 20
#define WW 64
#define NSENT (BB*RR*SS)   // 3200 word-level sequences
#define NREV  (BB*RR)      // 160 sentence-level sequences
#define G3    (3*HDIM)     // 384 gate rows per direction
#define NPROJ (2*G3)       // 768

// ---------------------------------------------------------------------------
// bf16 + fast-math helpers
// ---------------------------------------------------------------------------
static __device__ __forceinline__ short f2bf(float f) {    // RNE
    union { float f; unsigned u; } v; v.f = f;
    unsigned r = v.u + 0x7FFFu + ((v.u >> 16) & 1u);
    return (short)(r >> 16);
}
static __device__ __forceinline__ short f2bf_t(float f) {  // truncate
    union { float f; unsigned u; } v; v.f = f;
    return (short)(v.u >> 16);
}
static __device__ __forceinline__ float bf2f(short s) {
    union { unsigned u; float f; } v;
    v.u = ((unsigned)(unsigned short)s) << 16;
    return v.f;
}
static __device__ __forceinline__ float frcp(float x) {
    return __builtin_amdgcn_rcpf(x);
}
static __device__ __forceinline__ float fsigmoid(float x) {
    return frcp(1.f + __expf(-x));
}
static __device__ __forceinline__ float ftanh(float x) {
    float y = __expf(-2.f * fabsf(x));
    float t = (1.f - y) * frcp(1.f + y);
    return copysignf(t, x);
}

using bf16x8 = __attribute__((ext_vector_type(8))) short;
using f32x4  = __attribute__((ext_vector_type(4))) float;

// ---------------------------------------------------------------------------
// preconv_all: ONE launch converting all 4 weight matrices to split-bf16
// blobs (wWih_f/b: 200->224 pad; sWih_f/b: 128).
// ---------------------------------------------------------------------------
#define NG1 (384 * 224 / 8)   // 10752
#define NG2 (384 * 128 / 8)   // 6144

__global__ __launch_bounds__(256) void preconv_all(
    const float* __restrict__ wWih_f, const float* __restrict__ wWih_b,
    const float* __restrict__ sWih_f, const float* __restrict__ sWih_b,
    short* __restrict__ Bw_hi, short* __restrict__ Bw_lo,
    short* __restrict__ Sw_hi, short* __restrict__ Sw_lo)
{
    int g = blockIdx.x * 256 + threadIdx.x;
    const float* src; short* hi; short* lo; int KREAL, KPAD;
    if (g < NG1) {
        src = wWih_f; hi = Bw_hi; lo = Bw_lo; KREAL = 200; KPAD = 224;
    } else if (g < 2 * NG1) {
        g -= NG1;
        src = wWih_b; hi = Bw_hi + 384 * 224; lo = Bw_lo + 384 * 224;
        KREAL = 200; KPAD = 224;
    } else if (g < 2 * NG1 + NG2) {
        g -= 2 * NG1;
        src = sWih_f; hi = Sw_hi; lo = Sw_lo; KREAL = 128; KPAD = 128;
    } else if (g < 2 * NG1 + 2 * NG2) {
        g -= 2 * NG1 + NG2;
        src = sWih_b; hi = Sw_hi + 384 * 128; lo = Sw_lo + 384 * 128;
        KREAL = 128; KPAD = 128;
    } else return;

    int row = g / (KPAD / 8);
    int k   = (g % (KPAD / 8)) * 8;
    float v[8];
    if (k < KREAL) {
        const float* p = src + (size_t)row * KREAL + k;
        float4 a = *(const float4*)p;
        float4 b = *(const float4*)(p + 4);
        v[0]=a.x; v[1]=a.y; v[2]=a.z; v[3]=a.w;
        v[4]=b.x; v[5]=b.y; v[6]=b.z; v[7]=b.w;
    } else {
        #pragma unroll
        for (int j = 0; j < 8; ++j) v[j] = 0.f;
    }
    bf16x8 h, l;
    #pragma unroll
    for (int j = 0; j < 8; ++j) {
        short t = f2bf_t(v[j]);
        h[j] = t;
        l[j] = f2bf(v[j] - bf2f(t));
    }
    *(bf16x8*)&hi[(size_t)row * KPAD + k] = h;
    *(bf16x8*)&lo[(size_t)row * KPAD + k] = l;
}

// ---------------------------------------------------------------------------
// gemm_v5: split-bf16 MFMA GEMM, XCD-friendly grid (x=row-tile)
// + coalesced LDS-staged f32 epilogue. A converted in-kernel; B from blob.
// ---------------------------------------------------------------------------
template<int KREAL, int KPAD, bool AVG>
__global__ __launch_bounds__(256, 2) void gemm_v5(
    const float* __restrict__ A0, const float* __restrict__ A1, int M,
    const short* __restrict__ Bhi_g, const short* __restrict__ Blo_g,
    const float* __restrict__ bias0, const float* __restrict__ bias1,
    float* __restrict__ C)
{
    const int rt = blockIdx.x;
    const int ct = blockIdx.y;
    const int tid = threadIdx.x;
    const int lane = tid & 63;
    const int wid  = tid >> 6;
    const int rlane = lane & 15;
    const int kgrp  = lane >> 4;

    const int rowBase = rt * 128;
    const int colBase = ct * 128;

    __shared__ __align__(16) short smem[4 * 128 * 40];   // 40960 B
    short (*Ahi)[40] = (short(*)[40])(smem);
    short (*Alo)[40] = (short(*)[40])(smem + 5120);
    short (*Bhi)[40] = (short(*)[40])(smem + 10240);
    short (*Blo)[40] = (short(*)[40])(smem + 15360);

    const int wrow = (wid >> 1) * 64;
    const int wcol = (wid & 1) * 64;

    f32x4 acc[4][4];
    #pragma unroll
    for (int i = 0; i < 4; ++i)
        #pragma unroll
        for (int j = 0; j < 4; ++j) acc[i][j] = {0.f, 0.f, 0.f, 0.f};

    const int srow = tid >> 1;
    const int skh  = (tid & 1) << 4;
    const int grow = rowBase + srow;
    const size_t brow = (size_t)(colBase + srow) * KPAD;

    for (int k0 = 0; k0 < KPAD; k0 += 32) {
        {
            float v[16];
            #pragma unroll
            for (int i = 0; i < 4; ++i) {
                const int k = k0 + skh + i * 4;
                float4 x = {0.f, 0.f, 0.f, 0.f};
                if (grow < M && k + 3 < KREAL) {
                    x = *(const float4*)&A0[(size_t)grow * KREAL + k];
                    if (AVG) {
                        float4 y = *(const float4*)&A1[(size_t)grow * KREAL + k];
                        x.x = 0.5f * (x.x + y.x); x.y = 0.5f * (x.y + y.y);
                        x.z = 0.5f * (x.z + y.z); x.w = 0.5f * (x.w + y.w);
                    }
                }
                v[4*i+0] = x.x; v[4*i+1] = x.y; v[4*i+2] = x.z; v[4*i+3] = x.w;
            }
            bf16x8 h0, h1, l0, l1;
            #pragma unroll
            for (int i = 0; i < 8; ++i) {
                short a = f2bf_t(v[i]);
                h0[i] = a; l0[i] = f2bf(v[i] - bf2f(a));
                short b = f2bf_t(v[i + 8]);
                h1[i] = b; l1[i] = f2bf(v[i + 8] - bf2f(b));
            }
            *(bf16x8*)&Ahi[srow][skh]     = h0;
            *(bf16x8*)&Ahi[srow][skh + 8] = h1;
            *(bf16x8*)&Alo[srow][skh]     = l0;
            *(bf16x8*)&Alo[srow][skh + 8] = l1;
        }
        *(bf16x8*)&Bhi[srow][skh]     = *(const bf16x8*)&Bhi_g[brow + k0 + skh];
        *(bf16x8*)&Bhi[srow][skh + 8] = *(const bf16x8*)&Bhi_g[brow + k0 + skh + 8];
        *(bf16x8*)&Blo[srow][skh]     = *(const bf16x8*)&Blo_g[brow + k0 + skh];
        *(bf16x8*)&Blo[srow][skh + 8] = *(const bf16x8*)&Blo_g[brow + k0 + skh + 8];
        __syncthreads();
        bf16x8 ah[4], al[4], bh[4], bl[4];
        #pragma unroll
        for (int mr = 0; mr < 4; ++mr) {
            ah[mr] = *(const bf16x8*)&Ahi[wrow + mr * 16 + rlane][kgrp * 8];
            al[mr] = *(const bf16x8*)&Alo[wrow + mr * 16 + rlane][kgrp * 8];
        }
        #pragma unroll
        for (int nc = 0; nc < 4; ++nc) {
            bh[nc] = *(const bf16x8*)&Bhi[wcol + nc * 16 + rlane][kgrp * 8];
            bl[nc] = *(const bf16x8*)&Blo[wcol + nc * 16 + rlane][kgrp * 8];
        }
        #pragma unroll
        for (int mr = 0; mr < 4; ++mr)
            #pragma unroll
            for (int nc = 0; nc < 4; ++nc) {
                acc[mr][nc] = __builtin_amdgcn_mfma_f32_16x16x32_bf16(
                    ah[mr], bh[nc], acc[mr][nc], 0, 0, 0);
                acc[mr][nc] = __builtin_amdgcn_mfma_f32_16x16x32_bf16(
                    ah[mr], bl[nc], acc[mr][nc], 0, 0, 0);
                acc[mr][nc] = __builtin_amdgcn_mfma_f32_16x16x32_bf16(
                    al[mr], bh[nc], acc[mr][nc], 0, 0, 0);
            }
        __syncthreads();
    }

    const float* bs = (colBase < G3) ? bias0 : bias1;
    const int bcol = (colBase < G3) ? colBase : (colBase - G3);
    float* ldsf = (float*)smem;
    #pragma unroll
    for (int half = 0; half < 2; ++half) {
        __syncthreads();
        if ((wid & 1) == half) {
            #pragma unroll
            for (int nc = 0; nc < 4; ++nc) {
                const int c = nc * 16 + rlane;
                const float bv = bs[bcol + half * 64 + c];
                #pragma unroll
                for (int mr = 0; mr < 4; ++mr)
                    #pragma unroll
                    for (int r = 0; r < 4; ++r)
                        ldsf[(wrow + mr * 16 + kgrp * 4 + r) * 68 + c] =
                            acc[mr][nc][r] + bv;
            }
        }
        __syncthreads();
        const int row = tid >> 1;
        const int ch  = (tid & 1) * 32;
        if (rowBase + row < M) {
            float* cp = C + (size_t)(rowBase + row) * NPROJ
                          + colBase + half * 64 + ch;
            #pragma unroll
            for (int i = 0; i < 8; ++i)
                *(float4*)(cp + i * 4) = *(const float4*)&ldsf[row * 68 + ch + i * 4];
        }
    }
}

// ---------------------------------------------------------------------------
// Single-block counting sort for BOTH length arrays.
// ---------------------------------------------------------------------------
__global__ __launch_bounds__(256) void sort_all(
    const int* __restrict__ len1, int* __restrict__ order1,
    const int* __restrict__ len2, int* __restrict__ order2)
{
    __shared__ int hist[65];
    const int tid = threadIdx.x;

    for (int i = tid; i < 65; i += 256) hist[i] = 0;
    __syncthreads();
    for (int i = tid; i < NSENT; i += 256) atomicAdd(&hist[len1[i]], 1);
    __syncthreads();
    if (tid == 0) {
        int acc = 0;
        for (int l = 1; l <= WW; ++l) { int c = hist[l]; hist[l] = acc; acc += c; }
    }
    __syncthreads();
    for (int i = tid; i < NSENT; i += 256) {
        int pos = atomicAdd(&hist[len1[i]], 1);
        order1[pos] = i;
    }
    __syncthreads();
    for (int i = tid; i < 65; i += 256) hist[i] = 0;
    __syncthreads();
    for (int i = tid; i < NREV; i += 256) atomicAdd(&hist[len2[i]], 1);
    __syncthreads();
    if (tid == 0) {
        int acc = 0;
        for (int l = 1; l <= SS; ++l) { int c = hist[l]; hist[l] = acc; acc += c; }
    }
    __syncthreads();
    for (int i = tid; i < NREV; i += 256) {
        int pos = atomicAdd(&hist[len2[i]], 1);
        order2[pos] = i;
    }
}

// ---------------------------------------------------------------------------
// MFMA GRU scan, SINGLE-bf16 h recurrence: hg = [Whh_hi + Whh_lo] x bf16(h)
// (exactly W x bf16_rne(h); only h is rounded — weights stay split).
// 24 MFMA/step (8-deep chain), 4 ds_read_b128, LDS ~13 KB -> 2 blocks/CU.
// F32 table; fused gate; depth-2 xg prefetch via 2-body unroll; rcp gates.
// ---------------------------------------------------------------------------
template<bool WORD, int TMAX>
__global__ __launch_bounds__(512, 2) void gru_mfma(
    const float* __restrict__ table,
    const int*   __restrict__ tokens,
    const int*   __restrict__ lengths,
    const int*   __restrict__ order,
    const float* __restrict__ Whh_f, const float* __restrict__ Whh_b,
    const float* __restrict__ bhh_f, const float* __restrict__ bhh_b,
    float* __restrict__ hout_f, float* __restrict__ hout_b,
    int numSeq, int numTiles)
{
    const int dir  = (blockIdx.x >= numTiles) ? 1 : 0;
    const int rawt = dir ? (blockIdx.x - numTiles) : blockIdx.x;
    const int tile = numTiles - 1 - rawt;      // longest tiles first
    const int base = tile * 16;
    const int tid  = threadIdx.x;              // 0..511
    const int lane = tid & 63;
    const int wid  = tid >> 6;                 // 0..7
    const int rlane = lane & 15;
    const int kgrp  = lane >> 4;               // 0..3
    const int e = wid * 16 + rlane;            // this lane's gate element

    __shared__ __align__(16) short sh_hi[2][16][136];
    __shared__ int sh_len[16];
    __shared__ int sh_ord[16];
    __shared__ int sh_tok[WORD ? 16 * WW : 1];
    __shared__ int sh_maxlen;

    const float* Whh = dir ? Whh_b : Whh_f;
    const float* bhh = dir ? bhh_b : bhh_f;
    bf16x8 Bhi[3][4], Blo[3][4];
    float bb[3];
    #pragma unroll
    for (int nt = 0; nt < 3; ++nt) {
        const int cb = nt * HDIM + wid * 16;
        const float* wrow = Whh + (size_t)(cb + rlane) * HDIM;
        bb[nt] = bhh[cb + rlane];
        #pragma unroll
        for (int kc = 0; kc < 4; ++kc) {
            const float* wp = wrow + kc * 32 + kgrp * 8;
            float4 w0 = *(const float4*)wp;
            float4 w1 = *(const float4*)(wp + 4);
            float wv[8] = {w0.x, w0.y, w0.z, w0.w, w1.x, w1.y, w1.z, w1.w};
            #pragma unroll
            for (int j = 0; j < 8; ++j) {
                short hi = f2bf_t(wv[j]);
                Bhi[nt][kc][j] = hi;
                Blo[nt][kc][j] = f2bf(wv[j] - bf2f(hi));
            }
        }
    }

    if (tid < 16) {
        int pos = base + tid;
        int seq = (pos < numSeq) ? order[pos] : -1;
        sh_ord[tid] = seq;
        sh_len[tid] = (seq >= 0) ? lengths[seq] : 0;
    }
    __syncthreads();
    if (WORD) {
        for (int f = tid; f < 16 * WW; f += 512) {
            int s = f >> 6;
            int seq = sh_ord[s];
            sh_tok[f] = (seq >= 0) ? tokens[(size_t)seq * WW + (f & 63)] : 0;
        }
    }
    for (int u = tid; u < 2 * 16 * 136; u += 512)
        ((short*)sh_hi)[u] = 0;
    if (tid == 0) {
        int m = 0;
        for (int s = 0; s < 16; ++s) m = max(m, sh_len[s]);
        sh_maxlen = m;
    }
    int lens[4], ords[4];
    #pragma unroll
    for (int j = 0; j < 4; ++j) {
        lens[j] = sh_len[4 * kgrp + j];
        ords[j] = sh_ord[4 * kgrp + j];
    }
    __syncthreads();
    const int maxlen = sh_maxlen;

    auto fetch_xg = [&](int t, float* fr, float* fz, float* fn) {
        #pragma unroll
        for (int j = 0; j < 4; ++j) {
            fr[j] = 0.f; fz[j] = 0.f; fn[j] = 0.f;
            if (t < lens[j]) {
                int tt = dir ? (lens[j] - 1 - t) : t;
                size_t row;
                if (WORD) row = (size_t)sh_tok[(4 * kgrp + j) * WW + tt];
                else      row = (size_t)ords[j] * TMAX + tt;
                const float* xg = table + row * NPROJ + dir * G3 + e;
                fr[j] = xg[0]; fz[j] = xg[HDIM]; fn[j] = xg[2 * HDIM];
            }
        }
    };

    float hold[4] = {0.f, 0.f, 0.f, 0.f};
    float pAr[4], pAz[4], pAn[4];   // xg for even steps
    float pBr[4], pBz[4], pBn[4];   // xg for odd steps
    fetch_xg(0, pAr, pAz, pAn);
    fetch_xg(1, pBr, pBz, pBn);

#define GRU_STEP(T, PR, PZ, PN)                                               \
    {                                                                         \
        const int cur = (T) & 1, nxt = cur ^ 1;                               \
        bf16x8 ah[4];                                                         \
        _Pragma("unroll")                                                     \
        for (int kc = 0; kc < 4; ++kc)                                        \
            ah[kc] = *(const bf16x8*)&sh_hi[cur][rlane][kc * 32 + kgrp * 8];  \
        f32x4 acc[3];                                                         \
        _Pragma("unroll")                                                     \
        for (int nt = 0; nt < 3; ++nt) {                                      \
            acc[nt] = {0.f, 0.f, 0.f, 0.f};                                   \
            _Pragma("unroll")                                                 \
            for (int kc = 0; kc < 4; ++kc)                                    \
                acc[nt] = __builtin_amdgcn_mfma_f32_16x16x32_bf16(            \
                    ah[kc], Bhi[nt][kc], acc[nt], 0, 0, 0);                   \
            _Pragma("unroll")                                                 \
            for (int kc = 0; kc < 4; ++kc)                                    \
                acc[nt] = __builtin_amdgcn_mfma_f32_16x16x32_bf16(            \
                    ah[kc], Blo[nt][kc], acc[nt], 0, 0, 0);                   \
        }                                                                     \
        _Pragma("unroll")                                                     \
        for (int j = 0; j < 4; ++j) {                                         \
            if ((T) < lens[j]) {                                              \
                float hgr = acc[0][j] + bb[0];                                \
                float hgz = acc[1][j] + bb[1];                                \
                float hgn = acc[2][j] + bb[2];                                \
                float rg = fsigmoid(PR[j] + hgr);                             \
                float zg = fsigmoid(PZ[j] + hgz);                             \
                float ng = ftanh(PN[j] + rg * hgn);                           \
                hold[j] = (1.f - zg) * ng + zg * hold[j];                     \
            }                                                                 \
        }                                                                     \
        fetch_xg((T) + 2, PR, PZ, PN);                                        \
        _Pragma("unroll")                                                     \
        for (int j = 0; j < 4; ++j) {                                         \
            const int s = 4 * kgrp + j;                                       \
            sh_hi[nxt][s][e] = f2bf(hold[j]);                                 \
        }                                                                     \
        __syncthreads();                                                      \
    }

    int t = 0;
    for (; t + 1 < maxlen; t += 2) {
        GRU_STEP(t,     pAr, pAz, pAn);
        GRU_STEP(t + 1, pBr, pBz, pBn);
    }
    if (t < maxlen) {
        GRU_STEP(t, pAr, pAz, pAn);
    }
#undef GRU_STEP

    float* hout = dir ? hout_b : hout_f;
    #pragma unroll
    for (int j = 0; j < 4; ++j) {
        if (ords[j] >= 0)
            hout[(size_t)ords[j] * HDIM + e] = hold[j];
    }
}

// ---------------------------------------------------------------------------
// Head + mean
// ---------------------------------------------------------------------------
__global__ __launch_bounds__(64) void head_kernel(
    const float* __restrict__ hsf, const float* __restrict__ hsb,
    const float* __restrict__ fc1_w, const float* __restrict__ fc1_b,
    const float* __restrict__ fc2_w, const float* __restrict__ fc2_b,
    float* __restrict__ out)
{
    const int br = blockIdx.x;
    const int j = threadIdx.x;
    __shared__ float rev[HDIM];
    for (int ee = j; ee < HDIM; ee += 64)
        rev[ee] = 0.5f * (hsf[(size_t)br * HDIM + ee] + hsb[(size_t)br * HDIM + ee]);
    __syncthreads();
    float acc = 0.f;
    #pragma unroll
    for (int k = 0; k < HDIM; ++k)
        acc = fmaf(fc1_w[(size_t)j * HDIM + k], rev[k], acc);
    acc += fc1_b[j];
    const float alpha = 1.6732632423543772f;
    const float scale = 1.0507009873554805f;
    float h1 = scale * (acc > 0.f ? acc : alpha * (expf(acc) - 1.f));
    float contrib = h1 * fc2_w[j];
    #pragma unroll
    for (int off = 32; off > 0; off >>= 1)
        contrib += __shfl_down(contrib, off);
    if (j == 0) out[16 + br] = contrib + fc2_b[0];
}

__global__ void mean_kernel(float* __restrict__ out)
{
    int b = threadIdx.x;
    if (b < BB) {
        float s = 0.f;
        for (int r = 0; r < RR; ++r) s += out[16 + b * RR + r];
        out[b] = s / (float)RR;
    }
}

// ---------------------------------------------------------------------------
// Launch
// ---------------------------------------------------------------------------
extern "C" void kernel_launch(void* const* d_in, const int* in_sizes, int n_in,
                              void* d_out, int out_size, void* d_ws, size_t ws_size,
                              hipStream_t stream)
{
    const int*   inputs       = (const int*)d_in[0];
    const int*   sent_lengths = (const int*)d_in[1];
    const int*   sent_counts  = (const int*)d_in[2];
    const float* embed   = (const float*)d_in[3];
    const float* wWih_f  = (const float*)d_in[4];
    const float* wWhh_f  = (const float*)d_in[5];
    const float* wbih_f  = (const float*)d_in[6];
    const float* wbhh_f  = (const float*)d_in[7];
    const float* wWih_b  = (const float*)d_in[8];
    const float* wWhh_b  = (const float*)d_in[9];
    const float* wbih_b  = (const float*)d_in[10];
    const float* wbhh_b  = (const float*)d_in[11];
    const float* sWih_f  = (const float*)d_in[12];
    const float* sWhh_f  = (const float*)d_in[13];
    const float* sbih_f  = (const float*)d_in[14];
    const float* sbhh_f  = (const float*)d_in[15];
    const float* sWih_b  = (const float*)d_in[16];
    const float* sWhh_b  = (const float*)d_in[17];
    const float* sbih_b  = (const float*)d_in[18];
    const float* sbhh_b  = (const float*)d_in[19];
    const float* fc1_w   = (const float*)d_in[20];
    const float* fc1_b   = (const float*)d_in[21];
    const float* fc2_w   = (const float*)d_in[22];
    const float* fc2_b   = (const float*)d_in[23];

    float* ws = (float*)d_ws;
    const size_t projT_elems = (size_t)VOCAB * NPROJ;      // 38,400,000 f32
    const size_t xgs_elems   = (size_t)NSENT * NPROJ;      //  2,457,600 f32
    const size_t h_elems     = (size_t)NSENT * HDIM;       //    409,600 f32
    const size_t hs_elems    = (size_t)NREV * HDIM;        //     20,480 f32
    float* projT = ws;
    float* xgs   = projT + projT_elems;
    float* hf    = xgs + xgs_elems;
    float* hb    = hf + h_elems;
    float* hsf   = hb + h_elems;
    float* hsb   = hsf + hs_elems;
    int* order1  = (int*)(hsb + hs_elems);         // [NSENT]
    int* order2  = order1 + NSENT;                 // [NREV]
    short* Bw_hi = (short*)(order2 + NREV);        // [768*224]
    short* Bw_lo = Bw_hi + 768 * 224;
    short* Sw_hi = Bw_lo + 768 * 224;              // [768*128]
    short* Sw_lo = Sw_hi + 768 * 128;

    size_t need = (projT_elems + xgs_elems + 2*h_elems + 2*hs_elems) * sizeof(float)
                + (NSENT + NREV) * sizeof(int)
                + (size_t)(2 * 768 * 224 + 2 * 768 * 128) * sizeof(short);
    if (ws_size < need) return;

    // 0) counting sort + merged weight-blob preconversion
    sort_all<<<1, 256, 0, stream>>>(sent_lengths, order1, sent_counts, order2);
    {
        int ng = 2 * NG1 + 2 * NG2;                     // 33792 groups
        preconv_all<<<(ng + 255) / 256, 256, 0, stream>>>(
            wWih_f, wWih_b, sWih_f, sWih_b, Bw_hi, Bw_lo, Sw_hi, Sw_lo);
    }

    // 1) projected-embedding table (grid x=rt for XCD/L2-friendly A reads)
    {
        dim3 grid((VOCAB + 127) / 128, NPROJ / 128);    // 391 x 6
        gemm_v5<EDIM, 224, false><<<grid, 256, 0, stream>>>(
            embed, nullptr, VOCAB, Bw_hi, Bw_lo, wbih_f, wbih_b, projT);
    }
    // 2) word-level BiGRU last-h (single-bf16-h scan)
    {
        int numTiles = NSENT / 16;                      // 200
        gru_mfma<true, WW><<<2 * numTiles, 512, 0, stream>>>(
            projT, inputs, sent_lengths, order1,
            wWhh_f, wWhh_b, wbhh_f, wbhh_b,
            hf, hb, NSENT, numTiles);
    }
    // 3) sentence-level input projections
    {
        dim3 grid((NSENT + 127) / 128, NPROJ / 128);    // 25 x 6
        gemm_v5<HDIM, HDIM, true><<<grid, 256, 0, stream>>>(
            hf, hb, NSENT, Sw_hi, Sw_lo, sbih_f, sbih_b, xgs);
    }
    // 4) sentence-level BiGRU last-h
    {
        int numTiles = NREV / 16;                       // 10
        gru_mfma<false, SS><<<2 * numTiles, 512, 0, stream>>>(
            xgs, nullptr, sent_counts, order2,
            sWhh_f, sWhh_b, sbhh_f, sbhh_b,
            hsf, hsb, NREV, numTiles);
    }
    // 5) FC head -> r_stars, then p_stars
    head_kernel<<<NREV, 64, 0, stream>>>(hsf, hsb, fc1_w, fc1_b, fc2_w, fc2_b,
                                         (float*)d_out);
    mean_kernel<<<1, 64, 0, stream>>>((float*)d_out);
}